// Round 4
// baseline (6535.822 us; speedup 1.0000x reference)
//
#include <hip/hip_runtime.h>
#include <cstdint>
#include <cstddef>

// ---------------------------------------------------------------------------
// QRNN 2-bit forward, exact ternary-integer formulation.
// flags[0]=1 -> floats are f32 (else bf16); flags[1]=1 -> text is int64.
// Ternary vectors (len 1024) bit-packed as 32 u64: [2i]=plus, [2i+1]=nonzero.
// As uint4 i: (p.lo, p.hi, z.lo, z.hi) for elements 64i..64i+63.
// dot: both=hz&wz; neg=both&(hp^wp); k=popc(both)-2*popc(neg)
// Decision v = k*0.1+bias vs +-0.5 is monotone in k -> precomputed integer
// thresholds kp/km reproduce the f64 predicate bit-exactly.
//
// R-pipeline (k_pipe, 192 blocks = 64 A + 64 B + 64 C):
//   A = layer-0 recur (produces x_t), B = layer-1 input bit-GEMM (x_t -> n_t,
//   in-place into nbuf), C = layer-1 recur (consumes n_t).
// Fenceless handoff (R2, validated): all cross-stage data stores/loads are
// RELAXED+AGENT (sc0 sc1 -> write/read-through the IC, never dirty in L2 =>
// no wbl2). Flags are RELAXED agent stores issued AFTER __syncthreads()
// (the barrier's implicit s_waitcnt vmcnt(0) drain => all waves' IC stores
// visible first). Consumer data loads are control-dependent on observed flag
// values => ordered without acquire fences. Same-address flag stores are
// separated by barriers. Dependency graph acyclic (A never waits); 192
// blocks x 16 waves @ 1 block/CU co-resident on 256 CUs => no deadlock.
//
// R4: counters showed VGPR_Count=48 in EVERY version (incl. the 830us R0
// k_recur) — the 64 weight words were NEVER register-resident; the compiler
// re-loaded 16x buffer_load_dwordx4/thread/STEP = 256 KB L2->CU per CU-step.
// That fixed memory cost was the invariant limiter (R2==R3 despite different
// LDS/VALU mixes). Fix: pin weights in AGPRs (gfx950 unified RF) via
// volatile "a"-constraint asm (volatile so per-step reads can't be hoisted
// into 64 live VGPRs). 64 AGPR + ~40 VGPR < 128/wave cap at (1024,4).
// Also: all cross-step loads issued at TOP of step with distance 2-3 so the
// barrier's vmcnt(0) drain never exposes IC latency; split accumulators.
// ---------------------------------------------------------------------------

#define FLAG_STRIDE 16  // one flag per 64 B to avoid line contention

// AGPR pinning: volatile so GETs execute per use-site (no hoist-out-of-loop
// which would recreate 64 live VGPRs), PIN volatile so it isn't sunk.
#define AGPR_PIN(dst, src) \
  asm volatile("v_accvgpr_write_b32 %0, %1" : "=a"(dst) : "v"(src))
#define AGPR_GET(dst, src) \
  asm volatile("v_accvgpr_read_b32 %0, %1" : "=v"(dst) : "a"(src))

// bit-dot over 16 uint4 h-quads (uniform LDS reads) vs AGPR-pinned weights.
// Split accumulators halve the dependent add chain.
#define DOT16(HQ, SB, SN)                                                  \
  do {                                                                     \
    int _b0 = 0, _b1 = 0, _n0 = 0, _n1 = 0;                                \
    _Pragma("unroll")                                                      \
    for (int _i = 0; _i < 16; _i++) {                                      \
      uint4 _h = (HQ)[_i]; /* broadcast ds_read_b128 (uniform addr) */     \
      unsigned _wa, _wb, _wc, _wd;                                         \
      AGPR_GET(_wa, aw0[_i]); AGPR_GET(_wb, aw1[_i]);                      \
      AGPR_GET(_wc, aw2[_i]); AGPR_GET(_wd, aw3[_i]);                      \
      unsigned _blo = _h.z & _wc;                                          \
      unsigned _bhi = _h.w & _wd;                                          \
      unsigned _nlo = (_h.x ^ _wa) & _blo;                                 \
      unsigned _nhi = (_h.y ^ _wb) & _bhi;                                 \
      if (_i & 1) { _b1 += __popc(_blo) + __popc(_bhi);                    \
                    _n1 += __popc(_nlo) + __popc(_nhi); }                  \
      else        { _b0 += __popc(_blo) + __popc(_bhi);                    \
                    _n0 += __popc(_nlo) + __popc(_nhi); }                  \
    }                                                                      \
    SB = _b0 + _b1; SN = _n0 + _n1;                                        \
  } while (0)

// preload one packed row (16 uint4) into AGPR arrays aw0..aw3
#define WLOAD_AGPR(WROW)                                                   \
  unsigned aw0[16], aw1[16], aw2[16], aw3[16];                             \
  _Pragma("unroll")                                                        \
  for (int _i = 0; _i < 16; _i++) {                                        \
    uint4 _w4 = (WROW)[_i];                                                \
    AGPR_PIN(aw0[_i], _w4.x); AGPR_PIN(aw1[_i], _w4.y);                    \
    AGPR_PIN(aw2[_i], _w4.z); AGPR_PIN(aw3[_i], _w4.w);                    \
  }

static __device__ __forceinline__ float bf2f(unsigned short b) {
  return __uint_as_float(((unsigned)b) << 16);
}
static __device__ __forceinline__ unsigned short f2bf(float f) {
  unsigned u = __float_as_uint(f);
  u = (u + 0x7FFFu + ((u >> 16) & 1u)) >> 16;  // RNE
  return (unsigned short)u;
}
static __device__ __forceinline__ float loadw(const void* p, size_t i, int isf32) {
  return isf32 ? ((const float*)p)[i] : bf2f(((const unsigned short*)p)[i]);
}

__global__ __launch_bounds__(256) void k_detect(const unsigned short* __restrict__ embu,
                                                const int* __restrict__ text,
                                                int* __restrict__ flags) {
  int i = blockIdx.x * 256 + threadIdx.x;  // 65536 u16 samples: valid in either layout
  unsigned e = (embu[i] >> 7) & 0xFFu;     // bf16-view exponent field
  unsigned long long b = __ballot(e >= 127u);
  if ((threadIdx.x & 63) == 0 && b) atomicOr(&flags[0], 1);
  if (blockIdx.x == 0 && threadIdx.x == 0) {
    int allz = 1;
    for (int j = 0; j < 32; j++)
      if (text[2 * j + 1] != 0) allz = 0;   // first 256 B: valid in either layout
    flags[1] = allz;
  }
}

// vectorized max|emb|
__global__ __launch_bounds__(256) void k_maxabs(const uint4* __restrict__ w,
                                                const int* __restrict__ flags,
                                                unsigned* __restrict__ out) {
  int isf32 = flags[0];
  int n16 = isf32 ? 7680000 : 3840000;  // 30720000 elems / (4 or 8 per uint4)
  float mf = 0.f;
  unsigned mb = 0;
  int i = blockIdx.x * blockDim.x + threadIdx.x;
  int stride = gridDim.x * blockDim.x;
  if (isf32) {
    for (; i < n16; i += stride) {
      uint4 v = w[i];
      mf = fmaxf(mf, fabsf(__uint_as_float(v.x)));
      mf = fmaxf(mf, fabsf(__uint_as_float(v.y)));
      mf = fmaxf(mf, fabsf(__uint_as_float(v.z)));
      mf = fmaxf(mf, fabsf(__uint_as_float(v.w)));
    }
  } else {
    for (; i < n16; i += stride) {
      uint4 v = w[i];
      unsigned a;
      a = v.x & 0x7FFF7FFFu; mb = max(mb, a & 0xFFFFu); mb = max(mb, a >> 16);
      a = v.y & 0x7FFF7FFFu; mb = max(mb, a & 0xFFFFu); mb = max(mb, a >> 16);
      a = v.z & 0x7FFF7FFFu; mb = max(mb, a & 0xFFFFu); mb = max(mb, a >> 16);
      a = v.w & 0x7FFF7FFFu; mb = max(mb, a & 0xFFFFu); mb = max(mb, a >> 16);
    }
    mf = bf2f((unsigned short)mb);
  }
  for (int off = 32; off > 0; off >>= 1) mf = fmaxf(mf, __shfl_down(mf, off));
  __shared__ float red[4];
  if ((threadIdx.x & 63) == 0) red[threadIdx.x >> 6] = mf;
  __syncthreads();
  if (threadIdx.x == 0) {
    float b = fmaxf(fmaxf(red[0], red[1]), fmaxf(red[2], red[3]));
    atomicMax(out, __float_as_uint(b));  // b >= 0: bit pattern order-monotone
  }
}

__global__ __launch_bounds__(1024) void k_tern_rows(
    const void* __restrict__ Wih, const void* __restrict__ Whh,
    const void* __restrict__ fcw, const int* __restrict__ flags,
    unsigned long long* __restrict__ wim, unsigned long long* __restrict__ whm,
    unsigned long long* __restrict__ fcm) {
  int isf32 = flags[0];
  int b = blockIdx.x;  // 0..4099
  const void* src;
  size_t rowoff;
  unsigned long long* dst;
  if (b < 2048)      { src = Wih; rowoff = (size_t)b * 1024; dst = wim + (size_t)b * 32; }
  else if (b < 4096) { int r = b - 2048; src = Whh; rowoff = (size_t)r * 1024; dst = whm + (size_t)r * 32; }
  else               { int r = b - 4096; src = fcw; rowoff = (size_t)r * 1024; dst = fcm + (size_t)r * 32; }
  double w = (double)loadw(src, rowoff + threadIdx.x, isf32);
  unsigned long long bp = __ballot(w > 0.05);   // THR*W_SCALE, exact f64
  unsigned long long bm = __ballot(w < -0.05);
  if ((threadIdx.x & 63) == 0) {
    int wv = threadIdx.x >> 6;
    dst[2 * wv] = bp;
    dst[2 * wv + 1] = bp | bm;
  }
}

__global__ __launch_bounds__(1024) void k_embed(const int* __restrict__ text,
    const void* __restrict__ emb, const int* __restrict__ flags,
    const unsigned* __restrict__ mab, unsigned long long* __restrict__ x0) {
  int isf32 = flags[0], i64 = flags[1];
  int bt = blockIdx.x;
  long long tok = i64 ? ((const long long*)text)[bt] : (long long)text[bt];
  double ma = (double)__uint_as_float(*mab);
  float s = (float)exp2(ceil(log2(ma)));           // pow-2 scale (int_max = 1)
  float inv_s = 1.0f / s;                          // exact (pow-2)
  float w = loadw(emb, (size_t)tok * 1024 + threadIdx.x, isf32);
  float q = rintf(w * inv_s);                      // exact mul, half-even
  q = fminf(fmaxf(q, -2.0f), 1.0f);                // clip [-2, 1] (bw = 2)
  float val = q * s;                               // exact
  int code = (val > 0.5f) ? 1 : ((val < -0.5f) ? -1 : 0);
  unsigned long long bp = __ballot(code == 1);
  unsigned long long bm = __ballot(code == -1);
  if ((threadIdx.x & 63) == 0) {
    int wv = threadIdx.x >> 6;
    x0[(size_t)bt * 32 + 2 * wv] = bp;
    x0[(size_t)bt * 32 + 2 * wv + 1] = bp | bm;
  }
}

// ---- bit-GEMM (layer-0 pre-pass): n[bt][r] = <x_row[bt], Wi_row[r]> -------
__global__ __launch_bounds__(256, 4) void k_bitgemm(const unsigned long long* __restrict__ xm,
    const unsigned long long* __restrict__ wim, short* __restrict__ nbuf) {
  __shared__ __align__(16) uint4 lx[64 * 16];  // [bt][i] = (p.lo,p.hi,z.lo,z.hi)
  __shared__ unsigned any[64];
  int tid = threadIdx.x;
  int bt0 = blockIdx.x * 64;
  int r = blockIdx.y * 256 + tid;
  const uint4* wrow = (const uint4*)(wim + (size_t)r * 32);
  WLOAD_AGPR(wrow)
  if (tid < 64) any[tid] = 0;
  __syncthreads();
  unsigned accor = 0;
#pragma unroll
  for (int i = 0; i < 4; i++) {
    int idx = tid * 4 + i;  // 0..1023 uint4 slots, straight copy
    uint4 v = ((const uint4*)(xm + (size_t)bt0 * 32))[idx];
    lx[idx] = v;
    accor |= v.z | v.w;  // nonzero-mask halves
  }
  if (accor) atomicOr(&any[tid >> 2], 1u);  // 4 threads per bt row
  __syncthreads();
  for (int bt = 0; bt < 64; bt++) {
    int k = 0;
    if (any[bt]) {
      const uint4* hx = lx + bt * 16;
      int sb, sn;
      DOT16(hx, sb, sn);
      k = sb - 2 * sn;
    }
    nbuf[(size_t)(bt0 + bt) * 1024 + r] = (short)k;
  }
}

// ---- fused 3-stage pipeline ----------------------------------------------

static __device__ __forceinline__ int ldflag(const int* p) {
  return __hip_atomic_load(p, __ATOMIC_RELAXED, __HIP_MEMORY_SCOPE_AGENT);
}
static __device__ __forceinline__ void stflag(int* p, int v) {
  __hip_atomic_store(p, v, __ATOMIC_RELAXED, __HIP_MEMORY_SCOPE_AGENT);
}
static __device__ __forceinline__ unsigned long long ldu64(const unsigned long long* p) {
  return __hip_atomic_load(p, __ATOMIC_RELAXED, __HIP_MEMORY_SCOPE_AGENT);
}
static __device__ __forceinline__ int lds16(const short* p) {
  return (int)__hip_atomic_load(p, __ATOMIC_RELAXED, __HIP_MEMORY_SCOPE_AGENT);
}

// ROLE 0 = layer-0 recur (producer of x_t); ROLE 2 = layer-1 recur (consumer)
template <int ROLE>
static __device__ __forceinline__ void recur_stage(
    uint4 (*shb)[16], const short* nbuf,
    const unsigned long long* __restrict__ whm,
    const void* __restrict__ bih, const void* __restrict__ bhh,
    int isf32, int layer, int b, int r,
    unsigned long long* xrow,              // ROLE 0 only
    int* flagsA, int* flagsB,
    unsigned long long* __restrict__ hidm) {
  const uint4* wrow = (const uint4*)(whm + (size_t)(layer * 1024 + r) * 32);
  WLOAD_AGPR(wrow)
  size_t boff = (size_t)layer * 1024 + r;
  double bias = (double)loadw(bih, boff, isf32) + (double)loadw(bhh, boff, isf32);
  // exact integer thresholds reproducing the f64 predicate
  int kp = (int)ceil((0.5 - bias) * 10.0);
  while ((double)kp * 0.1 + bias <= 0.5) kp++;
  while ((double)(kp - 1) * 0.1 + bias > 0.5) kp--;
  int km = (int)floor((-0.5 - bias) * 10.0);
  while ((double)km * 0.1 + bias >= -0.5) km--;
  while ((double)(km + 1) * 0.1 + bias < -0.5) km++;

  if (r < 32) ((unsigned long long*)shb)[r] = 0;  // zero buffer 0
  const short* nrow = nbuf + (size_t)b * 512 * 1024 + r;
  int wv = r >> 6;
  bool l0 = (r & 63) == 0;
  int fb = 0;   // ROLE 2: cached flagsB
  int* flagsAp = flagsA + b * FLAG_STRIDE;
  int* flagsBp = flagsB + b * FLAG_STRIDE;
  int nin, nin1;
  if (ROLE == 0) {  // pre-pass data: plain loads fine
    nin  = (int)nrow[0];
    nin1 = (int)nrow[1024];
  } else {
    while ((fb = ldflag(flagsBp)) < 2) {}
    // data load control-dependent on flag value => ordered, no acquire needed
    nin  = lds16(nrow);
    nin1 = lds16(nrow + 1024);
  }
  __syncthreads();
  int pb = 0;
  unsigned long long plo = 0, phi = 0;  // ROLE 0, l0 lanes: deferred x words
  for (int t = 0; t < 512; t++) {
    // ---- top of step: issue ALL memory ops (acks covered by the dot) ----
    if (ROLE == 0 && l0 && t > 0) {  // deferred store of x_{t-1}
      __hip_atomic_store(xrow + (size_t)(t - 1) * 32 + 2 * wv, plo,
                         __ATOMIC_RELAXED, __HIP_MEMORY_SCOPE_AGENT);
      __hip_atomic_store(xrow + (size_t)(t - 1) * 32 + 2 * wv + 1, phi,
                         __ATOMIC_RELAXED, __HIP_MEMORY_SCOPE_AGENT);
    }
    int nin2 = 0;
    bool got = true;
    if (t < 510) {  // distance-2 prefetch of n_{t+2}
      if (ROLE == 0) {
        nin2 = (int)nrow[(size_t)(t + 2) * 1024];
      } else {
        if (fb < t + 3) fb = ldflag(flagsBp);
        got = (fb >= t + 3);
        if (got) nin2 = lds16(nrow + (size_t)(t + 2) * 1024);
      }
    }
    // ---- dot over current h ----
    const uint4* Hq = shb[pb];
    int sb, sn;
    DOT16(Hq, sb, sn);
    int k = nin + sb - 2 * sn;
    unsigned long long bp = __ballot(k >= kp);
    unsigned long long bm = __ballot(k <= km);
    unsigned long long bz = bp | bm;
    if (l0) {
      uint4 o;
      o.x = (unsigned)bp; o.y = (unsigned)(bp >> 32);
      o.z = (unsigned)bz; o.w = (unsigned)(bz >> 32);
      shb[pb ^ 1][wv] = o;
      plo = bp; phi = bz;  // defer global store to next step
    }
    if (ROLE == 2 && t < 510 && !got) {  // cold path: pipeline fill only
      while ((fb = ldflag(flagsBp)) < t + 3) {}
      nin2 = lds16(nrow + (size_t)(t + 2) * 1024);
    }
    __syncthreads();  // implicit vmcnt(0)+lgkmcnt(0): stores/loads drained
    // publish AFTER barrier: all waves' stores of x[<=t-1] globally visible.
    if (ROLE == 0 && r == 0 && t > 0) stflag(flagsAp, t);
    pb ^= 1;
    nin = nin1;
    nin1 = nin2;
  }
  if (ROLE == 0) {  // commit x[511], then final publish
    if (l0) {
      __hip_atomic_store(xrow + (size_t)511 * 32 + 2 * wv, plo,
                         __ATOMIC_RELAXED, __HIP_MEMORY_SCOPE_AGENT);
      __hip_atomic_store(xrow + (size_t)511 * 32 + 2 * wv + 1, phi,
                         __ATOMIC_RELAXED, __HIP_MEMORY_SCOPE_AGENT);
    }
    __syncthreads();  // drains the stores
    if (r == 0) stflag(flagsAp, 512);
  }
  if (r < 16) {  // final h is in shb[pb]
    uint4 h = shb[pb][r];
    size_t ho = (size_t)(layer * 64 + b) * 32;
    hidm[ho + 2 * r]     = ((unsigned long long)h.y << 32) | h.x;
    hidm[ho + 2 * r + 1] = ((unsigned long long)h.w << 32) | h.z;
  }
}

__global__ __launch_bounds__(1024, 4) void k_pipe(
    short* nbuf, unsigned long long* x0,
    const unsigned long long* __restrict__ wim,
    const unsigned long long* __restrict__ whm,
    const void* __restrict__ bih, const void* __restrict__ bhh,
    const int* __restrict__ flags, int* flagsA, int* flagsB,
    unsigned long long* __restrict__ hidm) {
  __shared__ __align__(16) uint4 shb[2][16];
  int role = blockIdx.x % 3;  // interleave roles across XCDs
  int b = blockIdx.x / 3;
  int r = threadIdx.x;
  int isf32 = flags[0];
  if (role == 0) {
    recur_stage<0>(shb, nbuf, whm, bih, bhh, isf32, 0, b, r,
                   x0 + (size_t)b * 512 * 32, flagsA, flagsB, hidm);
  } else if (role == 1) {
    // ---- stage B: layer-1 input bit-GEMM, trailing A by ~4 steps ----------
    // Invariants at top of step t: LDS buf[t&1] = x_t; vnext = x_{t+1};
    // v2 = x_{t+2} (r<32); ncur = n_{t-1} (t>0, in register).
    const uint4* wrow = (const uint4*)(wim + (size_t)(1024 + r) * 32);
    WLOAD_AGPR(wrow)
    const unsigned long long* xsrc = x0 + (size_t)b * 512 * 32;
    short* nout = nbuf + (size_t)b * 512 * 1024 + r;
    int* flagsAp = flagsA + b * FLAG_STRIDE;
    int* flagsBp = flagsB + b * FLAG_STRIDE;
    int fa = 0;
    unsigned long long vnext = 0, v2 = 0;
    if (r < 32) {  // prologue: x_0 -> buf[0]; x_1, x_2 -> regs
      while ((fa = ldflag(flagsAp)) < 1) {}
      ((unsigned long long*)(shb[0]))[r] = ldu64(xsrc + r);
      while (fa < 2) { fa = ldflag(flagsAp); }
      vnext = ldu64(xsrc + 32 + r);
      while (fa < 3) { fa = ldflag(flagsAp); }
      v2 = ldu64(xsrc + 64 + r);
    }
    __syncthreads();
    short ncur = 0;
    for (int t = 0; t < 512; t++) {
      // top of step: LDS-write x_{t+1}; store n_{t-1}; issue load x_{t+3}
      if (r < 32 && t < 511) ((unsigned long long*)(shb[(t + 1) & 1]))[r] = vnext;
      if (t > 0)
        __hip_atomic_store(nout + (size_t)(t - 1) * 1024, ncur,
                           __ATOMIC_RELAXED, __HIP_MEMORY_SCOPE_AGENT);
      bool got = true;
      unsigned long long v3 = 0;
      if (r < 32 && t < 509) {  // distance-3 prefetch
        if (fa < t + 4) fa = ldflag(flagsAp);
        got = (fa >= t + 4);
        if (got) v3 = ldu64(xsrc + (size_t)(t + 3) * 32 + r);
      }
      const uint4* hx = shb[t & 1];
      int sb, sn;
      DOT16(hx, sb, sn);
      if (r < 32 && t < 509 && !got) {  // cold path: pipeline fill only
        while ((fa = ldflag(flagsAp)) < t + 4) {}
        v3 = ldu64(xsrc + (size_t)(t + 3) * 32 + r);
      }
      __syncthreads();   // drains n-store + x-load; buf[(t+1)&1] visible
      if (r == 0 && t > 0) stflag(flagsBp, t);  // n[0..t-1] committed
      ncur = (short)(sb - 2 * sn);
      vnext = v2;
      v2 = v3;
    }
    // epilogue: commit n_511, publish full
    __hip_atomic_store(nout + (size_t)511 * 1024, ncur,
                       __ATOMIC_RELAXED, __HIP_MEMORY_SCOPE_AGENT);
    __syncthreads();
    if (r == 0) stflag(flagsBp, 512);
  } else {
    recur_stage<2>(shb, nbuf, whm, bih, bhh, isf32, 1, b, r,
                   (unsigned long long*)0, flagsA, flagsB, hidm);
  }
}

__global__ __launch_bounds__(64) void k_fc(const unsigned long long* __restrict__ hidm,
    const unsigned long long* __restrict__ fcm, const int* __restrict__ flags,
    void* __restrict__ out) {
  int isf32 = flags[0];
  int lb = blockIdx.x, lane = threadIdx.x;
  unsigned long long hp = 0, hz = 0;
  if (lane < 16) {
    hp = hidm[lb * 32 + 2 * lane];
    hz = hidm[lb * 32 + 2 * lane + 1];
  }
#pragma unroll
  for (int o = 0; o < 4; o++) {
    int k = 0;
    if (lane < 16) {
      unsigned long long wp = fcm[o * 32 + 2 * lane], wz = fcm[o * 32 + 2 * lane + 1];
      unsigned long long both = hz & wz;
      unsigned long long neg = both & (hp ^ wp);
      k = __popcll(both) - 2 * __popcll(neg);
    }
    for (int off = 8; off > 0; off >>= 1) k += __shfl_down(k, off);
    if (lane == 0) {
      float v = (float)((double)k * 0.1);
      if (isf32) ((float*)out)[lb * 4 + o] = v;
      else       ((unsigned short*)out)[lb * 4 + o] = f2bf(v);
    }
  }
}

extern "C" void kernel_launch(void* const* d_in, const int* in_sizes, int n_in,
                              void* d_out, int out_size, void* d_ws, size_t ws_size,
                              hipStream_t stream) {
  (void)in_sizes; (void)n_in; (void)out_size; (void)ws_size;
  const int* text = (const int*)d_in[0];
  // d_in[1] text_lengths: unused by the reference
  const void* emb = d_in[2];
  const void* Wih = d_in[3];
  const void* Whh = d_in[4];
  const void* bih = d_in[5];
  const void* bhh = d_in[6];
  const void* fcw = d_in[7];

  // workspace layout (~73 MB)
  char* ws = (char*)d_ws;
  int* flags = (int*)(ws);
  unsigned* mab = (unsigned*)(ws + 64);
  int* flagsA = (int*)(ws + 1024);   // 64 flags, stride 16 ints (4 KB)
  int* flagsB = (int*)(ws + 5120);   // 64 flags, stride 16 ints (4 KB)
  size_t off = 16384;
  unsigned long long* x0 = (unsigned long long*)(ws + off);  off += (size_t)32768 * 256;
  unsigned long long* wim = (unsigned long long*)(ws + off); off += (size_t)2048 * 256;
  unsigned long long* whm = (unsigned long long*)(ws + off); off += (size_t)2048 * 256;
  unsigned long long* fcm = (unsigned long long*)(ws + off); off += (size_t)4 * 256;
  unsigned long long* hidm = (unsigned long long*)(ws + off); off += (size_t)128 * 256;
  short* nbuf = (short*)(ws + off);                          off += (size_t)32768 * 1024 * 2;

  hipMemsetAsync(ws, 0, 16384, stream);  // flags, mab, flagsA, flagsB
  k_detect<<<256, 256, 0, stream>>>((const unsigned short*)emb, text, flags);
  k_maxabs<<<2048, 256, 0, stream>>>((const uint4*)emb, flags, mab);
  k_tern_rows<<<4100, 1024, 0, stream>>>(Wih, Whh, fcw, flags, wim, whm, fcm);
  k_embed<<<32768, 1024, 0, stream>>>(text, emb, flags, mab, x0);
  // layer-0 input gemm (x0 consumed; region then reused as layer-0 x-out)
  k_bitgemm<<<dim3(512, 4), 256, 0, stream>>>(x0, wim, nbuf);
  // fused pipeline: layer-0 recur || layer-1 bitgemm || layer-1 recur
  k_pipe<<<192, 1024, 0, stream>>>(nbuf, x0, wim, whm, bih, bhh, flags,
                                   flagsA, flagsB, hidm);
  k_fc<<<128, 64, 0, stream>>>(hidm, fcm, flags, d_out);
}

// Round 5
// 3485.793 us; speedup vs baseline: 1.8750x; 1.8750x over previous
//
#include <hip/hip_runtime.h>
#include <cstdint>
#include <cstddef>

// ---------------------------------------------------------------------------
// QRNN 2-bit forward, exact ternary-integer formulation.
// flags[0]=1 -> floats are f32 (else bf16); flags[1]=1 -> text is int64.
// Ternary vectors (len 1024) bit-packed as 32 u64: [2i]=plus, [2i+1]=nonzero.
// As uint4 i: (p.lo, p.hi, z.lo, z.hi) for elements 64i..64i+63.
// dot: both=hz&wz; neg=both&(hp^wp); k=popc(both)-2*popc(neg)
// Decision v = k*0.1+bias vs +-0.5 is monotone in k -> precomputed integer
// thresholds kp/km reproduce the f64 predicate bit-exactly.
//
// R-pipeline (k_pipe, 192 blocks = 64 A + 64 B + 64 C):
//   A = layer-0 recur (produces x_t), B = layer-1 input bit-GEMM (x_t -> n_t,
//   in-place into nbuf), C = layer-1 recur (consumes n_t).
// Fenceless handoff (R2, validated): all cross-stage data stores/loads are
// RELAXED+AGENT (sc0 sc1 -> write/read-through the IC, never dirty in L2 =>
// no wbl2). Flags are RELAXED agent stores issued AFTER __syncthreads()
// (the barrier's implicit s_waitcnt vmcnt(0) drain => all waves' IC stores
// visible first). Consumer data loads are control-dependent on observed flag
// values => ordered without acquire fences. Same-address flag stores are
// separated by barriers. Dependency graph acyclic (A never waits); 192
// blocks x 16 waves @ 1 block/CU co-resident on 256 CUs => no deadlock.
//
// R5: weight residency. R0-R3 ran at VGPR_Count=48: the compiler
// REMATERIALIZED the 64 weight words (16x buffer_load_dwordx4/thread/STEP =
// 256 KB L2->CU per CU-step ~= 2000-2900 cy) -- the invariant step-time
// floor. R4's volatile "a"-constraint AGPR pin backfired into scratch thrash
// (asm value constraints pin the operand site, not storage; 5.5 GB scratch).
// Fix: empty non-volatile asm with "+v" tie on each loaded word. Inline asm
// is not rematerializable => the 64 values MUST stay register-resident.
// 64 + ~40 other < 128 cap at (1024,4) => clean allocation, zero runtime
// cost. Dot reverted to R2-style broadcast ds_read_b128 (lowest VALU).
// ---------------------------------------------------------------------------

#define FLAG_STRIDE 16  // one flag per 64 B to avoid line contention

// Opacity pin: ties each weight word to a VGPR via a no-op asm. Not
// rematerializable => compiler cannot re-load it inside the step loop.
#define WLOAD_PIN(WROW)                                                    \
  unsigned wplo[16], wphi[16], wzlo[16], wzhi[16];                         \
  _Pragma("unroll")                                                        \
  for (int _i = 0; _i < 16; _i++) {                                        \
    uint4 _w4 = (WROW)[_i];                                                \
    asm("" : "+v"(_w4.x), "+v"(_w4.y), "+v"(_w4.z), "+v"(_w4.w));          \
    wplo[_i] = _w4.x; wphi[_i] = _w4.y;                                    \
    wzlo[_i] = _w4.z; wzhi[_i] = _w4.w;                                    \
  }

// bit-dot over 16 uint4 h-quads (wave-uniform broadcast ds_read_b128) vs
// register-resident weights. Split accumulators shorten dependent chains;
// __popc(x) + acc fuses to v_bcnt_u32_b32 accumulate form.
#define DOT16(HQ, SB, SN)                                                  \
  do {                                                                     \
    int _b0 = 0, _b1 = 0, _n0 = 0, _n1 = 0;                                \
    _Pragma("unroll")                                                      \
    for (int _i = 0; _i < 16; _i++) {                                      \
      uint4 _h = (HQ)[_i]; /* broadcast ds_read_b128 (uniform addr) */     \
      unsigned _blo = _h.z & wzlo[_i];                                     \
      unsigned _bhi = _h.w & wzhi[_i];                                     \
      unsigned _nlo = (_h.x ^ wplo[_i]) & _blo;                            \
      unsigned _nhi = (_h.y ^ wphi[_i]) & _bhi;                            \
      if (_i & 1) { _b1 += __popc(_blo); _b1 += __popc(_bhi);              \
                    _n1 += __popc(_nlo); _n1 += __popc(_nhi); }            \
      else        { _b0 += __popc(_blo); _b0 += __popc(_bhi);              \
                    _n0 += __popc(_nlo); _n0 += __popc(_nhi); }            \
    }                                                                      \
    SB = _b0 + _b1; SN = _n0 + _n1;                                        \
  } while (0)

static __device__ __forceinline__ float bf2f(unsigned short b) {
  return __uint_as_float(((unsigned)b) << 16);
}
static __device__ __forceinline__ unsigned short f2bf(float f) {
  unsigned u = __float_as_uint(f);
  u = (u + 0x7FFFu + ((u >> 16) & 1u)) >> 16;  // RNE
  return (unsigned short)u;
}
static __device__ __forceinline__ float loadw(const void* p, size_t i, int isf32) {
  return isf32 ? ((const float*)p)[i] : bf2f(((const unsigned short*)p)[i]);
}

__global__ __launch_bounds__(256) void k_detect(const unsigned short* __restrict__ embu,
                                                const int* __restrict__ text,
                                                int* __restrict__ flags) {
  int i = blockIdx.x * 256 + threadIdx.x;  // 65536 u16 samples: valid in either layout
  unsigned e = (embu[i] >> 7) & 0xFFu;     // bf16-view exponent field
  unsigned long long b = __ballot(e >= 127u);
  if ((threadIdx.x & 63) == 0 && b) atomicOr(&flags[0], 1);
  if (blockIdx.x == 0 && threadIdx.x == 0) {
    int allz = 1;
    for (int j = 0; j < 32; j++)
      if (text[2 * j + 1] != 0) allz = 0;   // first 256 B: valid in either layout
    flags[1] = allz;
  }
}

// vectorized max|emb|
__global__ __launch_bounds__(256) void k_maxabs(const uint4* __restrict__ w,
                                                const int* __restrict__ flags,
                                                unsigned* __restrict__ out) {
  int isf32 = flags[0];
  int n16 = isf32 ? 7680000 : 3840000;  // 30720000 elems / (4 or 8 per uint4)
  float mf = 0.f;
  unsigned mb = 0;
  int i = blockIdx.x * blockDim.x + threadIdx.x;
  int stride = gridDim.x * blockDim.x;
  if (isf32) {
    for (; i < n16; i += stride) {
      uint4 v = w[i];
      mf = fmaxf(mf, fabsf(__uint_as_float(v.x)));
      mf = fmaxf(mf, fabsf(__uint_as_float(v.y)));
      mf = fmaxf(mf, fabsf(__uint_as_float(v.z)));
      mf = fmaxf(mf, fabsf(__uint_as_float(v.w)));
    }
  } else {
    for (; i < n16; i += stride) {
      uint4 v = w[i];
      unsigned a;
      a = v.x & 0x7FFF7FFFu; mb = max(mb, a & 0xFFFFu); mb = max(mb, a >> 16);
      a = v.y & 0x7FFF7FFFu; mb = max(mb, a & 0xFFFFu); mb = max(mb, a >> 16);
      a = v.z & 0x7FFF7FFFu; mb = max(mb, a & 0xFFFFu); mb = max(mb, a >> 16);
      a = v.w & 0x7FFF7FFFu; mb = max(mb, a & 0xFFFFu); mb = max(mb, a >> 16);
    }
    mf = bf2f((unsigned short)mb);
  }
  for (int off = 32; off > 0; off >>= 1) mf = fmaxf(mf, __shfl_down(mf, off));
  __shared__ float red[4];
  if ((threadIdx.x & 63) == 0) red[threadIdx.x >> 6] = mf;
  __syncthreads();
  if (threadIdx.x == 0) {
    float b = fmaxf(fmaxf(red[0], red[1]), fmaxf(red[2], red[3]));
    atomicMax(out, __float_as_uint(b));  // b >= 0: bit pattern order-monotone
  }
}

__global__ __launch_bounds__(1024) void k_tern_rows(
    const void* __restrict__ Wih, const void* __restrict__ Whh,
    const void* __restrict__ fcw, const int* __restrict__ flags,
    unsigned long long* __restrict__ wim, unsigned long long* __restrict__ whm,
    unsigned long long* __restrict__ fcm) {
  int isf32 = flags[0];
  int b = blockIdx.x;  // 0..4099
  const void* src;
  size_t rowoff;
  unsigned long long* dst;
  if (b < 2048)      { src = Wih; rowoff = (size_t)b * 1024; dst = wim + (size_t)b * 32; }
  else if (b < 4096) { int r = b - 2048; src = Whh; rowoff = (size_t)r * 1024; dst = whm + (size_t)r * 32; }
  else               { int r = b - 4096; src = fcw; rowoff = (size_t)r * 1024; dst = fcm + (size_t)r * 32; }
  double w = (double)loadw(src, rowoff + threadIdx.x, isf32);
  unsigned long long bp = __ballot(w > 0.05);   // THR*W_SCALE, exact f64
  unsigned long long bm = __ballot(w < -0.05);
  if ((threadIdx.x & 63) == 0) {
    int wv = threadIdx.x >> 6;
    dst[2 * wv] = bp;
    dst[2 * wv + 1] = bp | bm;
  }
}

__global__ __launch_bounds__(1024) void k_embed(const int* __restrict__ text,
    const void* __restrict__ emb, const int* __restrict__ flags,
    const unsigned* __restrict__ mab, unsigned long long* __restrict__ x0) {
  int isf32 = flags[0], i64 = flags[1];
  int bt = blockIdx.x;
  long long tok = i64 ? ((const long long*)text)[bt] : (long long)text[bt];
  double ma = (double)__uint_as_float(*mab);
  float s = (float)exp2(ceil(log2(ma)));           // pow-2 scale (int_max = 1)
  float inv_s = 1.0f / s;                          // exact (pow-2)
  float w = loadw(emb, (size_t)tok * 1024 + threadIdx.x, isf32);
  float q = rintf(w * inv_s);                      // exact mul, half-even
  q = fminf(fmaxf(q, -2.0f), 1.0f);                // clip [-2, 1] (bw = 2)
  float val = q * s;                               // exact
  int code = (val > 0.5f) ? 1 : ((val < -0.5f) ? -1 : 0);
  unsigned long long bp = __ballot(code == 1);
  unsigned long long bm = __ballot(code == -1);
  if ((threadIdx.x & 63) == 0) {
    int wv = threadIdx.x >> 6;
    x0[(size_t)bt * 32 + 2 * wv] = bp;
    x0[(size_t)bt * 32 + 2 * wv + 1] = bp | bm;
  }
}

// ---- bit-GEMM (layer-0 pre-pass): n[bt][r] = <x_row[bt], Wi_row[r]> -------
__global__ __launch_bounds__(256, 4) void k_bitgemm(const unsigned long long* __restrict__ xm,
    const unsigned long long* __restrict__ wim, short* __restrict__ nbuf) {
  __shared__ __align__(16) uint4 lx[64 * 16];  // [bt][i] = (p.lo,p.hi,z.lo,z.hi)
  __shared__ unsigned any[64];
  int tid = threadIdx.x;
  int bt0 = blockIdx.x * 64;
  int r = blockIdx.y * 256 + tid;
  const uint4* wrow = (const uint4*)(wim + (size_t)r * 32);
  WLOAD_PIN(wrow)
  if (tid < 64) any[tid] = 0;
  __syncthreads();
  unsigned accor = 0;
#pragma unroll
  for (int i = 0; i < 4; i++) {
    int idx = tid * 4 + i;  // 0..1023 uint4 slots, straight copy
    uint4 v = ((const uint4*)(xm + (size_t)bt0 * 32))[idx];
    lx[idx] = v;
    accor |= v.z | v.w;  // nonzero-mask halves
  }
  if (accor) atomicOr(&any[tid >> 2], 1u);  // 4 threads per bt row
  __syncthreads();
  for (int bt = 0; bt < 64; bt++) {
    int k = 0;
    if (any[bt]) {
      const uint4* hx = lx + bt * 16;
      int sb, sn;
      DOT16(hx, sb, sn);
      k = sb - 2 * sn;
    }
    nbuf[(size_t)(bt0 + bt) * 1024 + r] = (short)k;
  }
}

// ---- fused 3-stage pipeline ----------------------------------------------

static __device__ __forceinline__ int ldflag(const int* p) {
  return __hip_atomic_load(p, __ATOMIC_RELAXED, __HIP_MEMORY_SCOPE_AGENT);
}
static __device__ __forceinline__ void stflag(int* p, int v) {
  __hip_atomic_store(p, v, __ATOMIC_RELAXED, __HIP_MEMORY_SCOPE_AGENT);
}
static __device__ __forceinline__ unsigned long long ldu64(const unsigned long long* p) {
  return __hip_atomic_load(p, __ATOMIC_RELAXED, __HIP_MEMORY_SCOPE_AGENT);
}
static __device__ __forceinline__ int lds16(const short* p) {
  return (int)__hip_atomic_load(p, __ATOMIC_RELAXED, __HIP_MEMORY_SCOPE_AGENT);
}

// ROLE 0 = layer-0 recur (producer of x_t); ROLE 2 = layer-1 recur (consumer)
template <int ROLE>
static __device__ __forceinline__ void recur_stage(
    uint4 (*shb)[16], const short* nbuf,
    const unsigned long long* __restrict__ whm,
    const void* __restrict__ bih, const void* __restrict__ bhh,
    int isf32, int layer, int b, int r,
    unsigned long long* xrow,              // ROLE 0 only
    int* flagsA, int* flagsB,
    unsigned long long* __restrict__ hidm) {
  const uint4* wrow = (const uint4*)(whm + (size_t)(layer * 1024 + r) * 32);
  WLOAD_PIN(wrow)
  size_t boff = (size_t)layer * 1024 + r;
  double bias = (double)loadw(bih, boff, isf32) + (double)loadw(bhh, boff, isf32);
  // exact integer thresholds reproducing the f64 predicate
  int kp = (int)ceil((0.5 - bias) * 10.0);
  while ((double)kp * 0.1 + bias <= 0.5) kp++;
  while ((double)(kp - 1) * 0.1 + bias > 0.5) kp--;
  int km = (int)floor((-0.5 - bias) * 10.0);
  while ((double)km * 0.1 + bias >= -0.5) km--;
  while ((double)(km + 1) * 0.1 + bias < -0.5) km++;

  if (r < 32) ((unsigned long long*)shb)[r] = 0;  // zero buffer 0
  const short* nrow = nbuf + (size_t)b * 512 * 1024 + r;
  int wv = r >> 6;
  bool l0 = (r & 63) == 0;
  int fb = 0;   // ROLE 2: cached flagsB
  int* flagsAp = flagsA + b * FLAG_STRIDE;
  int* flagsBp = flagsB + b * FLAG_STRIDE;
  int nin, nin1;
  if (ROLE == 0) {  // pre-pass data: plain loads fine
    nin  = (int)nrow[0];
    nin1 = (int)nrow[1024];
  } else {
    while ((fb = ldflag(flagsBp)) < 2) {}
    // data load control-dependent on flag value => ordered, no acquire needed
    nin  = lds16(nrow);
    nin1 = lds16(nrow + 1024);
  }
  __syncthreads();
  int pb = 0;
  unsigned long long plo = 0, phi = 0;  // ROLE 0, l0 lanes: deferred x words
  for (int t = 0; t < 512; t++) {
    // ---- top of step: issue ALL memory ops (acks covered by the dot) ----
    if (ROLE == 0 && l0 && t > 0) {  // deferred store of x_{t-1}
      __hip_atomic_store(xrow + (size_t)(t - 1) * 32 + 2 * wv, plo,
                         __ATOMIC_RELAXED, __HIP_MEMORY_SCOPE_AGENT);
      __hip_atomic_store(xrow + (size_t)(t - 1) * 32 + 2 * wv + 1, phi,
                         __ATOMIC_RELAXED, __HIP_MEMORY_SCOPE_AGENT);
    }
    int nin2 = 0;
    bool got = true;
    if (t < 510) {  // distance-2 prefetch of n_{t+2}
      if (ROLE == 0) {
        nin2 = (int)nrow[(size_t)(t + 2) * 1024];
      } else {
        if (fb < t + 3) fb = ldflag(flagsBp);
        got = (fb >= t + 3);
        if (got) nin2 = lds16(nrow + (size_t)(t + 2) * 1024);
      }
    }
    // ---- dot over current h ----
    const uint4* Hq = shb[pb];
    int sb, sn;
    DOT16(Hq, sb, sn);
    int k = nin + sb - 2 * sn;
    unsigned long long bp = __ballot(k >= kp);
    unsigned long long bm = __ballot(k <= km);
    unsigned long long bz = bp | bm;
    if (l0) {
      uint4 o;
      o.x = (unsigned)bp; o.y = (unsigned)(bp >> 32);
      o.z = (unsigned)bz; o.w = (unsigned)(bz >> 32);
      shb[pb ^ 1][wv] = o;
      plo = bp; phi = bz;  // defer global store to next step
    }
    if (ROLE == 2 && t < 510 && !got) {  // cold path: pipeline fill only
      while ((fb = ldflag(flagsBp)) < t + 3) {}
      nin2 = lds16(nrow + (size_t)(t + 2) * 1024);
    }
    __syncthreads();  // implicit vmcnt(0)+lgkmcnt(0): stores/loads drained
    // publish AFTER barrier: all waves' stores of x[<=t-1] globally visible.
    if (ROLE == 0 && r == 0 && t > 0) stflag(flagsAp, t);
    pb ^= 1;
    nin = nin1;
    nin1 = nin2;
  }
  if (ROLE == 0) {  // commit x[511], then final publish
    if (l0) {
      __hip_atomic_store(xrow + (size_t)511 * 32 + 2 * wv, plo,
                         __ATOMIC_RELAXED, __HIP_MEMORY_SCOPE_AGENT);
      __hip_atomic_store(xrow + (size_t)511 * 32 + 2 * wv + 1, phi,
                         __ATOMIC_RELAXED, __HIP_MEMORY_SCOPE_AGENT);
    }
    __syncthreads();  // drains the stores
    if (r == 0) stflag(flagsAp, 512);
  }
  if (r < 16) {  // final h is in shb[pb]
    uint4 h = shb[pb][r];
    size_t ho = (size_t)(layer * 64 + b) * 32;
    hidm[ho + 2 * r]     = ((unsigned long long)h.y << 32) | h.x;
    hidm[ho + 2 * r + 1] = ((unsigned long long)h.w << 32) | h.z;
  }
}

__global__ __launch_bounds__(1024, 4) void k_pipe(
    short* nbuf, unsigned long long* x0,
    const unsigned long long* __restrict__ wim,
    const unsigned long long* __restrict__ whm,
    const void* __restrict__ bih, const void* __restrict__ bhh,
    const int* __restrict__ flags, int* flagsA, int* flagsB,
    unsigned long long* __restrict__ hidm) {
  __shared__ __align__(16) uint4 shb[2][16];
  int role = blockIdx.x % 3;  // interleave roles across XCDs
  int b = blockIdx.x / 3;
  int r = threadIdx.x;
  int isf32 = flags[0];
  if (role == 0) {
    recur_stage<0>(shb, nbuf, whm, bih, bhh, isf32, 0, b, r,
                   x0 + (size_t)b * 512 * 32, flagsA, flagsB, hidm);
  } else if (role == 1) {
    // ---- stage B: layer-1 input bit-GEMM, trailing A by ~4 steps ----------
    // Invariants at top of step t: LDS buf[t&1] = x_t; vnext = x_{t+1};
    // v2 = x_{t+2} (r<32); ncur = n_{t-1} (t>0, in register).
    const uint4* wrow = (const uint4*)(wim + (size_t)(1024 + r) * 32);
    WLOAD_PIN(wrow)
    const unsigned long long* xsrc = x0 + (size_t)b * 512 * 32;
    short* nout = nbuf + (size_t)b * 512 * 1024 + r;
    int* flagsAp = flagsA + b * FLAG_STRIDE;
    int* flagsBp = flagsB + b * FLAG_STRIDE;
    int fa = 0;
    unsigned long long vnext = 0, v2 = 0;
    if (r < 32) {  // prologue: x_0 -> buf[0]; x_1, x_2 -> regs
      while ((fa = ldflag(flagsAp)) < 1) {}
      ((unsigned long long*)(shb[0]))[r] = ldu64(xsrc + r);
      while (fa < 2) { fa = ldflag(flagsAp); }
      vnext = ldu64(xsrc + 32 + r);
      while (fa < 3) { fa = ldflag(flagsAp); }
      v2 = ldu64(xsrc + 64 + r);
    }
    __syncthreads();
    short ncur = 0;
    for (int t = 0; t < 512; t++) {
      // top of step: LDS-write x_{t+1}; store n_{t-1}; issue load x_{t+3}
      if (r < 32 && t < 511) ((unsigned long long*)(shb[(t + 1) & 1]))[r] = vnext;
      if (t > 0)
        __hip_atomic_store(nout + (size_t)(t - 1) * 1024, ncur,
                           __ATOMIC_RELAXED, __HIP_MEMORY_SCOPE_AGENT);
      bool got = true;
      unsigned long long v3 = 0;
      if (r < 32 && t < 509) {  // distance-3 prefetch
        if (fa < t + 4) fa = ldflag(flagsAp);
        got = (fa >= t + 4);
        if (got) v3 = ldu64(xsrc + (size_t)(t + 3) * 32 + r);
      }
      const uint4* hx = shb[t & 1];
      int sb, sn;
      DOT16(hx, sb, sn);
      if (r < 32 && t < 509 && !got) {  // cold path: pipeline fill only
        while ((fa = ldflag(flagsAp)) < t + 4) {}
        v3 = ldu64(xsrc + (size_t)(t + 3) * 32 + r);
      }
      __syncthreads();   // drains n-store + x-load; buf[(t+1)&1] visible
      if (r == 0 && t > 0) stflag(flagsBp, t);  // n[0..t-1] committed
      ncur = (short)(sb - 2 * sn);
      vnext = v2;
      v2 = v3;
    }
    // epilogue: commit n_511, publish full
    __hip_atomic_store(nout + (size_t)511 * 1024, ncur,
                       __ATOMIC_RELAXED, __HIP_MEMORY_SCOPE_AGENT);
    __syncthreads();
    if (r == 0) stflag(flagsBp, 512);
  } else {
    recur_stage<2>(shb, nbuf, whm, bih, bhh, isf32, 1, b, r,
                   (unsigned long long*)0, flagsA, flagsB, hidm);
  }
}

__global__ __launch_bounds__(64) void k_fc(const unsigned long long* __restrict__ hidm,
    const unsigned long long* __restrict__ fcm, const int* __restrict__ flags,
    void* __restrict__ out) {
  int isf32 = flags[0];
  int lb = blockIdx.x, lane = threadIdx.x;
  unsigned long long hp = 0, hz = 0;
  if (lane < 16) {
    hp = hidm[lb * 32 + 2 * lane];
    hz = hidm[lb * 32 + 2 * lane + 1];
  }
#pragma unroll
  for (int o = 0; o < 4; o++) {
    int k = 0;
    if (lane < 16) {
      unsigned long long wp = fcm[o * 32 + 2 * lane], wz = fcm[o * 32 + 2 * lane + 1];
      unsigned long long both = hz & wz;
      unsigned long long neg = both & (hp ^ wp);
      k = __popcll(both) - 2 * __popcll(neg);
    }
    for (int off = 8; off > 0; off >>= 1) k += __shfl_down(k, off);
    if (lane == 0) {
      float v = (float)((double)k * 0.1);
      if (isf32) ((float*)out)[lb * 4 + o] = v;
      else       ((unsigned short*)out)[lb * 4 + o] = f2bf(v);
    }
  }
}

extern "C" void kernel_launch(void* const* d_in, const int* in_sizes, int n_in,
                              void* d_out, int out_size, void* d_ws, size_t ws_size,
                              hipStream_t stream) {
  (void)in_sizes; (void)n_in; (void)out_size; (void)ws_size;
  const int* text = (const int*)d_in[0];
  // d_in[1] text_lengths: unused by the reference
  const void* emb = d_in[2];
  const void* Wih = d_in[3];
  const void* Whh = d_in[4];
  const void* bih = d_in[5];
  const void* bhh = d_in[6];
  const void* fcw = d_in[7];

  // workspace layout (~73 MB)
  char* ws = (char*)d_ws;
  int* flags = (int*)(ws);
  unsigned* mab = (unsigned*)(ws + 64);
  int* flagsA = (int*)(ws + 1024);   // 64 flags, stride 16 ints (4 KB)
  int* flagsB = (int*)(ws + 5120);   // 64 flags, stride 16 ints (4 KB)
  size_t off = 16384;
  unsigned long long* x0 = (unsigned long long*)(ws + off);  off += (size_t)32768 * 256;
  unsigned long long* wim = (unsigned long long*)(ws + off); off += (size_t)2048 * 256;
  unsigned long long* whm = (unsigned long long*)(ws + off); off += (size_t)2048 * 256;
  unsigned long long* fcm = (unsigned long long*)(ws + off); off += (size_t)4 * 256;
  unsigned long long* hidm = (unsigned long long*)(ws + off); off += (size_t)128 * 256;
  short* nbuf = (short*)(ws + off);                          off += (size_t)32768 * 1024 * 2;

  hipMemsetAsync(ws, 0, 16384, stream);  // flags, mab, flagsA, flagsB
  k_detect<<<256, 256, 0, stream>>>((const unsigned short*)emb, text, flags);
  k_maxabs<<<2048, 256, 0, stream>>>((const uint4*)emb, flags, mab);
  k_tern_rows<<<4100, 1024, 0, stream>>>(Wih, Whh, fcw, flags, wim, whm, fcm);
  k_embed<<<32768, 1024, 0, stream>>>(text, emb, flags, mab, x0);
  // layer-0 input gemm (x0 consumed; region then reused as layer-0 x-out)
  k_bitgemm<<<dim3(512, 4), 256, 0, stream>>>(x0, wim, nbuf);
  // fused pipeline: layer-0 recur || layer-1 bitgemm || layer-1 recur
  k_pipe<<<192, 1024, 0, stream>>>(nbuf, x0, wim, whm, bih, bhh, flags,
                                   flagsA, flagsB, hidm);
  k_fc<<<128, 64, 0, stream>>>(hidm, fcm, flags, d_out);
}

// Round 6
// 2504.578 us; speedup vs baseline: 2.6095x; 1.3918x over previous
//
#include <hip/hip_runtime.h>
#include <cstdint>
#include <cstddef>

// ---------------------------------------------------------------------------
// QRNN 2-bit forward, exact ternary-integer formulation.
// flags[0]=1 -> floats are f32 (else bf16); flags[1]=1 -> text is int64.
// Ternary vectors (len 1024) bit-packed as 32 u64: [2i]=plus, [2i+1]=nonzero.
// As uint4 i: (p.lo, p.hi, z.lo, z.hi) for elements 64i..64i+63.
// dot: both=hz&wz; neg=both&(hp^wp); k=popc(both)-2*popc(neg)
// Decision v = k*0.1+bias vs +-0.5 is monotone in k -> precomputed integer
// thresholds kp/km reproduce the f64 predicate bit-exactly.
//
// R-pipeline (k_pipe, 192 blocks = 64 A + 64 B + 64 C):
//   A = layer-0 recur (produces x_t), B = layer-1 input bit-GEMM (x_t -> n_t,
//   in-place into nbuf), C = layer-1 recur (consumes n_t).
// Fenceless handoff (R2, validated): all cross-stage data stores/loads are
// RELAXED+AGENT (sc0 sc1 -> write/read-through the IC, never dirty in L2 =>
// no wbl2). Flags are RELAXED agent stores issued AFTER __syncthreads()
// (the barrier's implicit vmcnt(0) drain => all waves' IC stores visible
// first). Consumer data loads are control-dependent on observed flag values
// => ordered without acquire fences. Same-address flag stores separated by
// barriers. Dependency graph acyclic; 192 blocks co-resident => no deadlock.
//
// R6: WEIGHT RESIDENCY VIA REGISTER BUDGET, not allocator tricks.
// R0-R3: (1024,4) => 128-VGPR cap; allocator pressure (64 words + dot
// temps + LDS in-flight) > 128 => remat from L2 = 256 KB/CU-step stream =
// the invariant ~5500cy step floor. R4 (AGPR pin) and R5 ("+v" tie) only
// moved the spill to scratch (5.5 GB WRITE / 1.3 GB FETCH disasters).
// Fix: 512 threads/block, 2 ROWS PER THREAD, __launch_bounds__(512,2) =>
// 2 waves/EU => 256-VGPR budget. 128 weight words + ~50 overhead ~= 180
// << 256 => plain C arrays stay resident (no asm). Same total work/CU;
// ballots produce mask words w and w+8 per wave. Tell-tale: VGPR_Count
// must jump to ~170+.
// ---------------------------------------------------------------------------

#define FLAG_STRIDE 16  // one flag per 64 B to avoid line contention

static __device__ __forceinline__ float bf2f(unsigned short b) {
  return __uint_as_float(((unsigned)b) << 16);
}
static __device__ __forceinline__ unsigned short f2bf(float f) {
  unsigned u = __float_as_uint(f);
  u = (u + 0x7FFFu + ((u >> 16) & 1u)) >> 16;  // RNE
  return (unsigned short)u;
}
static __device__ __forceinline__ float loadw(const void* p, size_t i, int isf32) {
  return isf32 ? ((const float*)p)[i] : bf2f(((const unsigned short*)p)[i]);
}

__global__ __launch_bounds__(256) void k_detect(const unsigned short* __restrict__ embu,
                                                const int* __restrict__ text,
                                                int* __restrict__ flags) {
  int i = blockIdx.x * 256 + threadIdx.x;  // 65536 u16 samples: valid in either layout
  unsigned e = (embu[i] >> 7) & 0xFFu;     // bf16-view exponent field
  unsigned long long b = __ballot(e >= 127u);
  if ((threadIdx.x & 63) == 0 && b) atomicOr(&flags[0], 1);
  if (blockIdx.x == 0 && threadIdx.x == 0) {
    int allz = 1;
    for (int j = 0; j < 32; j++)
      if (text[2 * j + 1] != 0) allz = 0;   // first 256 B: valid in either layout
    flags[1] = allz;
  }
}

// vectorized max|emb|
__global__ __launch_bounds__(256) void k_maxabs(const uint4* __restrict__ w,
                                                const int* __restrict__ flags,
                                                unsigned* __restrict__ out) {
  int isf32 = flags[0];
  int n16 = isf32 ? 7680000 : 3840000;  // 30720000 elems / (4 or 8 per uint4)
  float mf = 0.f;
  unsigned mb = 0;
  int i = blockIdx.x * blockDim.x + threadIdx.x;
  int stride = gridDim.x * blockDim.x;
  if (isf32) {
    for (; i < n16; i += stride) {
      uint4 v = w[i];
      mf = fmaxf(mf, fabsf(__uint_as_float(v.x)));
      mf = fmaxf(mf, fabsf(__uint_as_float(v.y)));
      mf = fmaxf(mf, fabsf(__uint_as_float(v.z)));
      mf = fmaxf(mf, fabsf(__uint_as_float(v.w)));
    }
  } else {
    for (; i < n16; i += stride) {
      uint4 v = w[i];
      unsigned a;
      a = v.x & 0x7FFF7FFFu; mb = max(mb, a & 0xFFFFu); mb = max(mb, a >> 16);
      a = v.y & 0x7FFF7FFFu; mb = max(mb, a & 0xFFFFu); mb = max(mb, a >> 16);
      a = v.z & 0x7FFF7FFFu; mb = max(mb, a & 0xFFFFu); mb = max(mb, a >> 16);
      a = v.w & 0x7FFF7FFFu; mb = max(mb, a & 0xFFFFu); mb = max(mb, a >> 16);
    }
    mf = bf2f((unsigned short)mb);
  }
  for (int off = 32; off > 0; off >>= 1) mf = fmaxf(mf, __shfl_down(mf, off));
  __shared__ float red[4];
  if ((threadIdx.x & 63) == 0) red[threadIdx.x >> 6] = mf;
  __syncthreads();
  if (threadIdx.x == 0) {
    float b = fmaxf(fmaxf(red[0], red[1]), fmaxf(red[2], red[3]));
    atomicMax(out, __float_as_uint(b));  // b >= 0: bit pattern order-monotone
  }
}

__global__ __launch_bounds__(1024) void k_tern_rows(
    const void* __restrict__ Wih, const void* __restrict__ Whh,
    const void* __restrict__ fcw, const int* __restrict__ flags,
    unsigned long long* __restrict__ wim, unsigned long long* __restrict__ whm,
    unsigned long long* __restrict__ fcm) {
  int isf32 = flags[0];
  int b = blockIdx.x;  // 0..4099
  const void* src;
  size_t rowoff;
  unsigned long long* dst;
  if (b < 2048)      { src = Wih; rowoff = (size_t)b * 1024; dst = wim + (size_t)b * 32; }
  else if (b < 4096) { int r = b - 2048; src = Whh; rowoff = (size_t)r * 1024; dst = whm + (size_t)r * 32; }
  else               { int r = b - 4096; src = fcw; rowoff = (size_t)r * 1024; dst = fcm + (size_t)r * 32; }
  double w = (double)loadw(src, rowoff + threadIdx.x, isf32);
  unsigned long long bp = __ballot(w > 0.05);   // THR*W_SCALE, exact f64
  unsigned long long bm = __ballot(w < -0.05);
  if ((threadIdx.x & 63) == 0) {
    int wv = threadIdx.x >> 6;
    dst[2 * wv] = bp;
    dst[2 * wv + 1] = bp | bm;
  }
}

__global__ __launch_bounds__(1024) void k_embed(const int* __restrict__ text,
    const void* __restrict__ emb, const int* __restrict__ flags,
    const unsigned* __restrict__ mab, unsigned long long* __restrict__ x0) {
  int isf32 = flags[0], i64 = flags[1];
  int bt = blockIdx.x;
  long long tok = i64 ? ((const long long*)text)[bt] : (long long)text[bt];
  double ma = (double)__uint_as_float(*mab);
  float s = (float)exp2(ceil(log2(ma)));           // pow-2 scale (int_max = 1)
  float inv_s = 1.0f / s;                          // exact (pow-2)
  float w = loadw(emb, (size_t)tok * 1024 + threadIdx.x, isf32);
  float q = rintf(w * inv_s);                      // exact mul, half-even
  q = fminf(fmaxf(q, -2.0f), 1.0f);                // clip [-2, 1] (bw = 2)
  float val = q * s;                               // exact
  int code = (val > 0.5f) ? 1 : ((val < -0.5f) ? -1 : 0);
  unsigned long long bp = __ballot(code == 1);
  unsigned long long bm = __ballot(code == -1);
  if ((threadIdx.x & 63) == 0) {
    int wv = threadIdx.x >> 6;
    x0[(size_t)bt * 32 + 2 * wv] = bp;
    x0[(size_t)bt * 32 + 2 * wv + 1] = bp | bm;
  }
}

// ---- bit-GEMM (layer-0 pre-pass): n[bt][r] = <x_row[bt], Wi_row[r]> -------
// R0 form (weights remat from L2 each bt-iter is fine for a one-shot pass).
__global__ __launch_bounds__(256, 4) void k_bitgemm(const unsigned long long* __restrict__ xm,
    const unsigned long long* __restrict__ wim, short* __restrict__ nbuf) {
  __shared__ __align__(16) uint4 lx[64 * 16];  // [bt][i] = (p.lo,p.hi,z.lo,z.hi)
  __shared__ unsigned any[64];
  int tid = threadIdx.x;
  int bt0 = blockIdx.x * 64;
  int r = blockIdx.y * 256 + tid;
  unsigned wplo[16], wphi[16], wzlo[16], wzhi[16];
  const uint4* wrow = (const uint4*)(wim + (size_t)r * 32);
#pragma unroll
  for (int i = 0; i < 16; i++) {
    uint4 w4 = wrow[i];
    wplo[i] = w4.x; wphi[i] = w4.y; wzlo[i] = w4.z; wzhi[i] = w4.w;
  }
  if (tid < 64) any[tid] = 0;
  __syncthreads();
  unsigned accor = 0;
#pragma unroll
  for (int i = 0; i < 4; i++) {
    int idx = tid * 4 + i;  // 0..1023 uint4 slots, straight copy
    uint4 v = ((const uint4*)(xm + (size_t)bt0 * 32))[idx];
    lx[idx] = v;
    accor |= v.z | v.w;  // nonzero-mask halves
  }
  if (accor) atomicOr(&any[tid >> 2], 1u);  // 4 threads per bt row
  __syncthreads();
  for (int bt = 0; bt < 64; bt++) {
    int k = 0;
    if (any[bt]) {
      const uint4* hx = lx + bt * 16;
      int sb = 0, sn = 0;
#pragma unroll
      for (int i = 0; i < 16; i++) {
        uint4 h = hx[i];  // broadcast ds_read_b128
        unsigned blo = h.z & wzlo[i];
        unsigned bhi = h.w & wzhi[i];
        unsigned nlo = (h.x ^ wplo[i]) & blo;
        unsigned nhi = (h.y ^ wphi[i]) & bhi;
        sb += __popc(blo) + __popc(bhi);
        sn += __popc(nlo) + __popc(nhi);
      }
      k = sb - 2 * sn;
    }
    nbuf[(size_t)(bt0 + bt) * 1024 + r] = (short)k;
  }
}

// ---- fused 3-stage pipeline ----------------------------------------------

static __device__ __forceinline__ int ldflag(const int* p) {
  return __hip_atomic_load(p, __ATOMIC_RELAXED, __HIP_MEMORY_SCOPE_AGENT);
}
static __device__ __forceinline__ void stflag(int* p, int v) {
  __hip_atomic_store(p, v, __ATOMIC_RELAXED, __HIP_MEMORY_SCOPE_AGENT);
}
static __device__ __forceinline__ unsigned long long ldu64(const unsigned long long* p) {
  return __hip_atomic_load(p, __ATOMIC_RELAXED, __HIP_MEMORY_SCOPE_AGENT);
}
static __device__ __forceinline__ int lds16(const short* p) {
  return (int)__hip_atomic_load(p, __ATOMIC_RELAXED, __HIP_MEMORY_SCOPE_AGENT);
}
static __device__ __forceinline__ void stu64(unsigned long long* p, unsigned long long v) {
  __hip_atomic_store(p, v, __ATOMIC_RELAXED, __HIP_MEMORY_SCOPE_AGENT);
}

// load one packed weight row (16 uint4) into 4 unrolled arrays
#define WROW_LOAD(PFX, SRC)                                                \
  unsigned PFX##plo[16], PFX##phi[16], PFX##zlo[16], PFX##zhi[16];         \
  _Pragma("unroll")                                                        \
  for (int _i = 0; _i < 16; _i++) {                                        \
    uint4 _w4 = (SRC)[_i];                                                 \
    PFX##plo[_i] = _w4.x; PFX##phi[_i] = _w4.y;                            \
    PFX##zlo[_i] = _w4.z; PFX##zhi[_i] = _w4.w;                            \
  }

// dual-row bit-dot vs one h buffer (16 broadcast ds_read_b128), split accs
#define DOT2(HQ, K0, K1, NIN0, NIN1)                                       \
  int K0, K1;                                                              \
  do {                                                                     \
    int _s0a = 0, _s0b = 0, _n0a = 0, _n0b = 0;                            \
    int _s1a = 0, _s1b = 0, _n1a = 0, _n1b = 0;                            \
    _Pragma("unroll")                                                      \
    for (int _i = 0; _i < 16; _i++) {                                      \
      uint4 _h = (HQ)[_i]; /* broadcast ds_read_b128 (uniform addr) */     \
      unsigned _b, _c, _d, _e;                                             \
      _b = _h.z & a##zlo[_i];  _c = _h.w & a##zhi[_i];                     \
      _d = (_h.x ^ a##plo[_i]) & _b;  _e = (_h.y ^ a##phi[_i]) & _c;       \
      if (_i & 1) { _s0b += __popc(_b); _s0b += __popc(_c);                \
                    _n0b += __popc(_d); _n0b += __popc(_e); }              \
      else        { _s0a += __popc(_b); _s0a += __popc(_c);                \
                    _n0a += __popc(_d); _n0a += __popc(_e); }              \
      _b = _h.z & c##zlo[_i];  _c = _h.w & c##zhi[_i];                     \
      _d = (_h.x ^ c##plo[_i]) & _b;  _e = (_h.y ^ c##phi[_i]) & _c;       \
      if (_i & 1) { _s1b += __popc(_b); _s1b += __popc(_c);                \
                    _n1b += __popc(_d); _n1b += __popc(_e); }              \
      else        { _s1a += __popc(_b); _s1a += __popc(_c);                \
                    _n1a += __popc(_d); _n1a += __popc(_e); }              \
    }                                                                      \
    K0 = (NIN0) + (_s0a + _s0b) - 2 * (_n0a + _n0b);                       \
    K1 = (NIN1) + (_s1a + _s1b) - 2 * (_n1a + _n1b);                       \
  } while (0)

// integer thresholds reproducing the f64 predicate for one bias
static __device__ __forceinline__ void mk_thresh(double bias, int& kp, int& km) {
  kp = (int)ceil((0.5 - bias) * 10.0);
  while ((double)kp * 0.1 + bias <= 0.5) kp++;
  while ((double)(kp - 1) * 0.1 + bias > 0.5) kp--;
  km = (int)floor((-0.5 - bias) * 10.0);
  while ((double)km * 0.1 + bias >= -0.5) km--;
  while ((double)(km + 1) * 0.1 + bias < -0.5) km++;
}

// ROLE 0 = layer-0 recur (producer of x_t); ROLE 2 = layer-1 recur (consumer)
// 512 threads: thread r owns rows r and r+512 (mask words wv and wv+8).
template <int ROLE>
static __device__ __forceinline__ void recur_stage(
    uint4 (*shb)[16], const short* nbuf,
    const unsigned long long* __restrict__ whm,
    const void* __restrict__ bih, const void* __restrict__ bhh,
    int isf32, int layer, int b, int r,
    unsigned long long* xrow,              // ROLE 0 only
    int* flagsA, int* flagsB,
    unsigned long long* __restrict__ hidm) {
  const uint4* w0 = (const uint4*)(whm + (size_t)(layer * 1024 + r) * 32);
  const uint4* w1 = (const uint4*)(whm + (size_t)(layer * 1024 + r + 512) * 32);
  WROW_LOAD(a, w0)
  WROW_LOAD(c, w1)
  size_t boff = (size_t)layer * 1024 + r;
  double bias0 = (double)loadw(bih, boff, isf32) + (double)loadw(bhh, boff, isf32);
  double bias1 = (double)loadw(bih, boff + 512, isf32) + (double)loadw(bhh, boff + 512, isf32);
  int kp0, km0, kp1, km1;
  mk_thresh(bias0, kp0, km0);
  mk_thresh(bias1, kp1, km1);

  if (r < 32) ((unsigned long long*)shb)[r] = 0;  // zero buffer 0
  const short* nrow = nbuf + (size_t)b * 512 * 1024 + r;  // row1 at +512
  int wv = r >> 6;            // 0..7
  bool l0 = (r & 63) == 0;
  int fb = 0;   // ROLE 2: cached flagsB
  int* flagsAp = flagsA + b * FLAG_STRIDE;
  int* flagsBp = flagsB + b * FLAG_STRIDE;
  int n0_0, n0_1, n1_0, n1_1;  // nin[t], nin[t+1] for rows 0/1
  if (ROLE == 0) {  // pre-pass data: plain loads fine
    n0_0 = (int)nrow[0];    n1_0 = (int)nrow[512];
    n0_1 = (int)nrow[1024]; n1_1 = (int)nrow[1536];
  } else {
    while ((fb = ldflag(flagsBp)) < 2) {}
    // data loads control-dependent on flag value => ordered, no acquire
    n0_0 = lds16(nrow);        n1_0 = lds16(nrow + 512);
    n0_1 = lds16(nrow + 1024); n1_1 = lds16(nrow + 1536);
  }
  __syncthreads();
  int pb = 0;
  // ROLE 0, l0 lanes: deferred x words (rows group wv and wv+8)
  unsigned long long p0lo = 0, p0hi = 0, p1lo = 0, p1hi = 0;
  for (int t = 0; t < 512; t++) {
    // ---- top of step: issue ALL memory ops (acks covered by the dot) ----
    if (ROLE == 0 && l0 && t > 0) {  // deferred stores of x_{t-1}
      unsigned long long* xp = xrow + (size_t)(t - 1) * 32;
      stu64(xp + 2 * wv, p0lo);
      stu64(xp + 2 * wv + 1, p0hi);
      stu64(xp + 2 * (wv + 8), p1lo);
      stu64(xp + 2 * (wv + 8) + 1, p1hi);
    }
    int n0_2 = 0, n1_2 = 0;
    bool got = true;
    if (t < 510) {  // distance-2 prefetch of n_{t+2}
      const short* np = nrow + (size_t)(t + 2) * 1024;
      if (ROLE == 0) {
        n0_2 = (int)np[0]; n1_2 = (int)np[512];
      } else {
        if (fb < t + 3) fb = ldflag(flagsBp);
        got = (fb >= t + 3);
        if (got) { n0_2 = lds16(np); n1_2 = lds16(np + 512); }
      }
    }
    // ---- dual-row dot over current h ----
    const uint4* Hq = shb[pb];
    DOT2(Hq, k0, k1, n0_0, n1_0);
    unsigned long long bp0 = __ballot(k0 >= kp0);
    unsigned long long bz0 = bp0 | __ballot(k0 <= km0);
    unsigned long long bp1 = __ballot(k1 >= kp1);
    unsigned long long bz1 = bp1 | __ballot(k1 <= km1);
    if (l0) {
      uint4 o0, o1;
      o0.x = (unsigned)bp0; o0.y = (unsigned)(bp0 >> 32);
      o0.z = (unsigned)bz0; o0.w = (unsigned)(bz0 >> 32);
      o1.x = (unsigned)bp1; o1.y = (unsigned)(bp1 >> 32);
      o1.z = (unsigned)bz1; o1.w = (unsigned)(bz1 >> 32);
      shb[pb ^ 1][wv] = o0;
      shb[pb ^ 1][wv + 8] = o1;
      p0lo = bp0; p0hi = bz0; p1lo = bp1; p1hi = bz1;  // defer global store
    }
    if (ROLE == 2 && t < 510 && !got) {  // cold path: pipeline fill only
      while ((fb = ldflag(flagsBp)) < t + 3) {}
      const short* np = nrow + (size_t)(t + 2) * 1024;
      n0_2 = lds16(np); n1_2 = lds16(np + 512);
    }
    __syncthreads();  // implicit vmcnt(0)+lgkmcnt(0): stores/loads drained
    // publish AFTER barrier: all waves' stores of x[<=t-1] globally visible.
    if (ROLE == 0 && r == 0 && t > 0) stflag(flagsAp, t);
    pb ^= 1;
    n0_0 = n0_1; n0_1 = n0_2;
    n1_0 = n1_1; n1_1 = n1_2;
  }
  if (ROLE == 0) {  // commit x[511], then final publish
    if (l0) {
      unsigned long long* xp = xrow + (size_t)511 * 32;
      stu64(xp + 2 * wv, p0lo);
      stu64(xp + 2 * wv + 1, p0hi);
      stu64(xp + 2 * (wv + 8), p1lo);
      stu64(xp + 2 * (wv + 8) + 1, p1hi);
    }
    __syncthreads();  // drains the stores
    if (r == 0) stflag(flagsAp, 512);
  }
  if (r < 16) {  // final h is in shb[pb]
    uint4 h = shb[pb][r];
    size_t ho = (size_t)(layer * 64 + b) * 32;
    hidm[ho + 2 * r]     = ((unsigned long long)h.y << 32) | h.x;
    hidm[ho + 2 * r + 1] = ((unsigned long long)h.w << 32) | h.z;
  }
}

__global__ __launch_bounds__(512, 2) void k_pipe(
    short* nbuf, unsigned long long* x0,
    const unsigned long long* __restrict__ wim,
    const unsigned long long* __restrict__ whm,
    const void* __restrict__ bih, const void* __restrict__ bhh,
    const int* __restrict__ flags, int* flagsA, int* flagsB,
    unsigned long long* __restrict__ hidm) {
  __shared__ __align__(16) uint4 shb[2][16];
  int role = blockIdx.x % 3;  // interleave roles across XCDs
  int b = blockIdx.x / 3;
  int r = threadIdx.x;        // 0..511
  int isf32 = flags[0];
  if (role == 0) {
    recur_stage<0>(shb, nbuf, whm, bih, bhh, isf32, 0, b, r,
                   x0 + (size_t)b * 512 * 32, flagsA, flagsB, hidm);
  } else if (role == 1) {
    // ---- stage B: layer-1 input bit-GEMM, trailing A by ~4 steps ----------
    // Thread r owns output cols r and r+512. Invariants at top of step t:
    // LDS buf[t&1] = x_t; vnext = x_{t+1}; v2 = x_{t+2} (r<32);
    // ncur0/1 = n_{t-1} (t>0, in registers).
    const uint4* w0 = (const uint4*)(wim + (size_t)(1024 + r) * 32);
    const uint4* w1 = (const uint4*)(wim + (size_t)(1024 + r + 512) * 32);
    WROW_LOAD(a, w0)
    WROW_LOAD(c, w1)
    const unsigned long long* xsrc = x0 + (size_t)b * 512 * 32;
    short* nout = nbuf + (size_t)b * 512 * 1024 + r;  // col1 at +512
    int* flagsAp = flagsA + b * FLAG_STRIDE;
    int* flagsBp = flagsB + b * FLAG_STRIDE;
    int fa = 0;
    unsigned long long vnext = 0, v2 = 0;
    if (r < 32) {  // prologue: x_0 -> buf[0]; x_1, x_2 -> regs
      while ((fa = ldflag(flagsAp)) < 1) {}
      ((unsigned long long*)(shb[0]))[r] = ldu64(xsrc + r);
      while (fa < 2) { fa = ldflag(flagsAp); }
      vnext = ldu64(xsrc + 32 + r);
      while (fa < 3) { fa = ldflag(flagsAp); }
      v2 = ldu64(xsrc + 64 + r);
    }
    __syncthreads();
    short ncur0 = 0, ncur1 = 0;
    for (int t = 0; t < 512; t++) {
      // top of step: LDS-write x_{t+1}; store n_{t-1}; issue load x_{t+3}
      if (r < 32 && t < 511) ((unsigned long long*)(shb[(t + 1) & 1]))[r] = vnext;
      if (t > 0) {
        short* np = nout + (size_t)(t - 1) * 1024;
        __hip_atomic_store(np, ncur0, __ATOMIC_RELAXED, __HIP_MEMORY_SCOPE_AGENT);
        __hip_atomic_store(np + 512, ncur1, __ATOMIC_RELAXED, __HIP_MEMORY_SCOPE_AGENT);
      }
      bool got = true;
      unsigned long long v3 = 0;
      if (r < 32 && t < 509) {  // distance-3 prefetch
        if (fa < t + 4) fa = ldflag(flagsAp);
        got = (fa >= t + 4);
        if (got) v3 = ldu64(xsrc + (size_t)(t + 3) * 32 + r);
      }
      const uint4* hx = shb[t & 1];
      DOT2(hx, k0, k1, 0, 0);
      if (r < 32 && t < 509 && !got) {  // cold path: pipeline fill only
        while ((fa = ldflag(flagsAp)) < t + 4) {}
        v3 = ldu64(xsrc + (size_t)(t + 3) * 32 + r);
      }
      __syncthreads();   // drains n-store + x-load; buf[(t+1)&1] visible
      if (r == 0 && t > 0) stflag(flagsBp, t);  // n[0..t-1] committed
      ncur0 = (short)k0;
      ncur1 = (short)k1;
      vnext = v2;
      v2 = v3;
    }
    // epilogue: commit n_511, publish full
    {
      short* np = nout + (size_t)511 * 1024;
      __hip_atomic_store(np, ncur0, __ATOMIC_RELAXED, __HIP_MEMORY_SCOPE_AGENT);
      __hip_atomic_store(np + 512, ncur1, __ATOMIC_RELAXED, __HIP_MEMORY_SCOPE_AGENT);
    }
    __syncthreads();
    if (r == 0) stflag(flagsBp, 512);
  } else {
    recur_stage<2>(shb, nbuf, whm, bih, bhh, isf32, 1, b, r,
                   (unsigned long long*)0, flagsA, flagsB, hidm);
  }
}

__global__ __launch_bounds__(64) void k_fc(const unsigned long long* __restrict__ hidm,
    const unsigned long long* __restrict__ fcm, const int* __restrict__ flags,
    void* __restrict__ out) {
  int isf32 = flags[0];
  int lb = blockIdx.x, lane = threadIdx.x;
  unsigned long long hp = 0, hz = 0;
  if (lane < 16) {
    hp = hidm[lb * 32 + 2 * lane];
    hz = hidm[lb * 32 + 2 * lane + 1];
  }
#pragma unroll
  for (int o = 0; o < 4; o++) {
    int k = 0;
    if (lane < 16) {
      unsigned long long wp = fcm[o * 32 + 2 * lane], wz = fcm[o * 32 + 2 * lane + 1];
      unsigned long long both = hz & wz;
      unsigned long long neg = both & (hp ^ wp);
      k = __popcll(both) - 2 * __popcll(neg);
    }
    for (int off = 8; off > 0; off >>= 1) k += __shfl_down(k, off);
    if (lane == 0) {
      float v = (float)((double)k * 0.1);
      if (isf32) ((float*)out)[lb * 4 + o] = v;
      else       ((unsigned short*)out)[lb * 4 + o] = f2bf(v);
    }
  }
}

extern "C" void kernel_launch(void* const* d_in, const int* in_sizes, int n_in,
                              void* d_out, int out_size, void* d_ws, size_t ws_size,
                              hipStream_t stream) {
  (void)in_sizes; (void)n_in; (void)out_size; (void)ws_size;
  const int* text = (const int*)d_in[0];
  // d_in[1] text_lengths: unused by the reference
  const void* emb = d_in[2];
  const void* Wih = d_in[3];
  const void* Whh = d_in[4];
  const void* bih = d_in[5];
  const void* bhh = d_in[6];
  const void* fcw = d_in[7];

  // workspace layout (~73 MB)
  char* ws = (char*)d_ws;
  int* flags = (int*)(ws);
  unsigned* mab = (unsigned*)(ws + 64);
  int* flagsA = (int*)(ws + 1024);   // 64 flags, stride 16 ints (4 KB)
  int* flagsB = (int*)(ws + 5120);   // 64 flags, stride 16 ints (4 KB)
  size_t off = 16384;
  unsigned long long* x0 = (unsigned long long*)(ws + off);  off += (size_t)32768 * 256;
  unsigned long long* wim = (unsigned long long*)(ws + off); off += (size_t)2048 * 256;
  unsigned long long* whm = (unsigned long long*)(ws + off); off += (size_t)2048 * 256;
  unsigned long long* fcm = (unsigned long long*)(ws + off); off += (size_t)4 * 256;
  unsigned long long* hidm = (unsigned long long*)(ws + off); off += (size_t)128 * 256;
  short* nbuf = (short*)(ws + off);                          off += (size_t)32768 * 1024 * 2;

  hipMemsetAsync(ws, 0, 16384, stream);  // flags, mab, flagsA, flagsB
  k_detect<<<256, 256, 0, stream>>>((const unsigned short*)emb, text, flags);
  k_maxabs<<<2048, 256, 0, stream>>>((const uint4*)emb, flags, mab);
  k_tern_rows<<<4100, 1024, 0, stream>>>(Wih, Whh, fcw, flags, wim, whm, fcm);
  k_embed<<<32768, 1024, 0, stream>>>(text, emb, flags, mab, x0);
  // layer-0 input gemm (x0 consumed; region then reused as layer-0 x-out)
  k_bitgemm<<<dim3(512, 4), 256, 0, stream>>>(x0, wim, nbuf);
  // fused pipeline: layer-0 recur || layer-1 bitgemm || layer-1 recur
  k_pipe<<<192, 512, 0, stream>>>(nbuf, x0, wim, whm, bih, bhh, flags,
                                  flagsA, flagsB, hidm);
  k_fc<<<128, 64, 0, stream>>>(hidm, fcm, flags, d_out);
}

// Round 7
// 2101.346 us; speedup vs baseline: 3.1103x; 1.1919x over previous
//
#include <hip/hip_runtime.h>
#include <cstdint>
#include <cstddef>

// ---------------------------------------------------------------------------
// QRNN 2-bit forward, exact ternary-integer formulation.
// flags[0]=1 -> floats are f32 (else bf16); flags[1]=1 -> text is int64.
// Ternary vectors (len 1024) bit-packed as 32 u64: [2i]=plus, [2i+1]=nonzero.
// As uint4 i: (p.lo, p.hi, z.lo, z.hi) for elements 64i..64i+63.
// dot: both=hz&wz; neg=both&(hp^wp); k=popc(both)-2*popc(neg)
// Decision v = k*0.1+bias vs +-0.5 is monotone in k -> precomputed integer
// thresholds kp/km reproduce the f64 predicate bit-exactly.
//
// R-pipeline (k_pipe, 192 blocks = 64 A + 64 B + 64 C):
//   A = layer-0 recur (produces x_t), B = layer-1 input bit-GEMM (x_t -> n_t,
//   in-place into nbuf), C = layer-1 recur (consumes n_t).
// Fenceless handoff (R2, validated): all cross-stage data stores/loads are
// RELAXED+AGENT (sc0 sc1 -> write/read-through the IC, never dirty in L2 =>
// no wbl2). Flags are RELAXED agent stores issued AFTER __syncthreads()
// (the barrier's implicit vmcnt(0) drain => all waves' IC stores visible
// first). Consumer data loads are control-dependent on observed flag values
// => ordered without acquire fences. Same-address flag stores separated by
// barriers. Dependency graph acyclic; 192 blocks co-resident => no deadlock.
//
// R7: WEIGHT RESIDENCY VIA PRESSURE CONTROL.
// History: R0-R3 VGPR_Count=48/64 -- the 64 loop-invariant weight words were
// SUNK into the step loop (16x buffer_load_dwordx4/thread/step, 256 KB/CU-
// step L2 stream ~= 2000cy = the invariant floor). R4/R5 asm pins moved the
// spill to scratch (HBM disaster). R6 (512thr,2waves/EU) kept 128-VGPR
// remat AND halved occupancy (2 blocks/CU on 96 CUs) => 2x worse.
// Root cause of the sinking: the pre-RA scheduler CLUSTERS all 16
// ds_read_b128 h-loads of the unrolled dot => peak pressure = 64 weights +
// 64 h-words + temps > 128 cap => allocator sinks the weight loads.
// Fix: __builtin_amdgcn_sched_barrier(0) after each dot iteration -- no
// instruction crosses, max 1 h-quad live => pressure ~100 < 128 => weights
// stay resident. Per-iter ds_read latency is hidden by 4 waves/SIMD TLP.
// Tell-tale: VGPR_Count must rise to ~100+ with FETCH ~80 MB (no scratch).
// ---------------------------------------------------------------------------

#define FLAG_STRIDE 16  // one flag per 64 B to avoid line contention

static __device__ __forceinline__ float bf2f(unsigned short b) {
  return __uint_as_float(((unsigned)b) << 16);
}
static __device__ __forceinline__ unsigned short f2bf(float f) {
  unsigned u = __float_as_uint(f);
  u = (u + 0x7FFFu + ((u >> 16) & 1u)) >> 16;  // RNE
  return (unsigned short)u;
}
static __device__ __forceinline__ float loadw(const void* p, size_t i, int isf32) {
  return isf32 ? ((const float*)p)[i] : bf2f(((const unsigned short*)p)[i]);
}

__global__ __launch_bounds__(256) void k_detect(const unsigned short* __restrict__ embu,
                                                const int* __restrict__ text,
                                                int* __restrict__ flags) {
  int i = blockIdx.x * 256 + threadIdx.x;  // 65536 u16 samples: valid in either layout
  unsigned e = (embu[i] >> 7) & 0xFFu;     // bf16-view exponent field
  unsigned long long b = __ballot(e >= 127u);
  if ((threadIdx.x & 63) == 0 && b) atomicOr(&flags[0], 1);
  if (blockIdx.x == 0 && threadIdx.x == 0) {
    int allz = 1;
    for (int j = 0; j < 32; j++)
      if (text[2 * j + 1] != 0) allz = 0;   // first 256 B: valid in either layout
    flags[1] = allz;
  }
}

// vectorized max|emb|
__global__ __launch_bounds__(256) void k_maxabs(const uint4* __restrict__ w,
                                                const int* __restrict__ flags,
                                                unsigned* __restrict__ out) {
  int isf32 = flags[0];
  int n16 = isf32 ? 7680000 : 3840000;  // 30720000 elems / (4 or 8 per uint4)
  float mf = 0.f;
  unsigned mb = 0;
  int i = blockIdx.x * blockDim.x + threadIdx.x;
  int stride = gridDim.x * blockDim.x;
  if (isf32) {
    for (; i < n16; i += stride) {
      uint4 v = w[i];
      mf = fmaxf(mf, fabsf(__uint_as_float(v.x)));
      mf = fmaxf(mf, fabsf(__uint_as_float(v.y)));
      mf = fmaxf(mf, fabsf(__uint_as_float(v.z)));
      mf = fmaxf(mf, fabsf(__uint_as_float(v.w)));
    }
  } else {
    for (; i < n16; i += stride) {
      uint4 v = w[i];
      unsigned a;
      a = v.x & 0x7FFF7FFFu; mb = max(mb, a & 0xFFFFu); mb = max(mb, a >> 16);
      a = v.y & 0x7FFF7FFFu; mb = max(mb, a & 0xFFFFu); mb = max(mb, a >> 16);
      a = v.z & 0x7FFF7FFFu; mb = max(mb, a & 0xFFFFu); mb = max(mb, a >> 16);
      a = v.w & 0x7FFF7FFFu; mb = max(mb, a & 0xFFFFu); mb = max(mb, a >> 16);
    }
    mf = bf2f((unsigned short)mb);
  }
  for (int off = 32; off > 0; off >>= 1) mf = fmaxf(mf, __shfl_down(mf, off));
  __shared__ float red[4];
  if ((threadIdx.x & 63) == 0) red[threadIdx.x >> 6] = mf;
  __syncthreads();
  if (threadIdx.x == 0) {
    float b = fmaxf(fmaxf(red[0], red[1]), fmaxf(red[2], red[3]));
    atomicMax(out, __float_as_uint(b));  // b >= 0: bit pattern order-monotone
  }
}

__global__ __launch_bounds__(1024) void k_tern_rows(
    const void* __restrict__ Wih, const void* __restrict__ Whh,
    const void* __restrict__ fcw, const int* __restrict__ flags,
    unsigned long long* __restrict__ wim, unsigned long long* __restrict__ whm,
    unsigned long long* __restrict__ fcm) {
  int isf32 = flags[0];
  int b = blockIdx.x;  // 0..4099
  const void* src;
  size_t rowoff;
  unsigned long long* dst;
  if (b < 2048)      { src = Wih; rowoff = (size_t)b * 1024; dst = wim + (size_t)b * 32; }
  else if (b < 4096) { int r = b - 2048; src = Whh; rowoff = (size_t)r * 1024; dst = whm + (size_t)r * 32; }
  else               { int r = b - 4096; src = fcw; rowoff = (size_t)r * 1024; dst = fcm + (size_t)r * 32; }
  double w = (double)loadw(src, rowoff + threadIdx.x, isf32);
  unsigned long long bp = __ballot(w > 0.05);   // THR*W_SCALE, exact f64
  unsigned long long bm = __ballot(w < -0.05);
  if ((threadIdx.x & 63) == 0) {
    int wv = threadIdx.x >> 6;
    dst[2 * wv] = bp;
    dst[2 * wv + 1] = bp | bm;
  }
}

__global__ __launch_bounds__(1024) void k_embed(const int* __restrict__ text,
    const void* __restrict__ emb, const int* __restrict__ flags,
    const unsigned* __restrict__ mab, unsigned long long* __restrict__ x0) {
  int isf32 = flags[0], i64 = flags[1];
  int bt = blockIdx.x;
  long long tok = i64 ? ((const long long*)text)[bt] : (long long)text[bt];
  double ma = (double)__uint_as_float(*mab);
  float s = (float)exp2(ceil(log2(ma)));           // pow-2 scale (int_max = 1)
  float inv_s = 1.0f / s;                          // exact (pow-2)
  float w = loadw(emb, (size_t)tok * 1024 + threadIdx.x, isf32);
  float q = rintf(w * inv_s);                      // exact mul, half-even
  q = fminf(fmaxf(q, -2.0f), 1.0f);                // clip [-2, 1] (bw = 2)
  float val = q * s;                               // exact
  int code = (val > 0.5f) ? 1 : ((val < -0.5f) ? -1 : 0);
  unsigned long long bp = __ballot(code == 1);
  unsigned long long bm = __ballot(code == -1);
  if ((threadIdx.x & 63) == 0) {
    int wv = threadIdx.x >> 6;
    x0[(size_t)bt * 32 + 2 * wv] = bp;
    x0[(size_t)bt * 32 + 2 * wv + 1] = bp | bm;
  }
}

// ---- bit-GEMM (layer-0 pre-pass): n[bt][r] = <x_row[bt], Wi_row[r]> -------
// R0 form (weight remat from L2 per bt-iter is fine for a one-shot pass).
__global__ __launch_bounds__(256, 4) void k_bitgemm(const unsigned long long* __restrict__ xm,
    const unsigned long long* __restrict__ wim, short* __restrict__ nbuf) {
  __shared__ __align__(16) uint4 lx[64 * 16];  // [bt][i] = (p.lo,p.hi,z.lo,z.hi)
  __shared__ unsigned any[64];
  int tid = threadIdx.x;
  int bt0 = blockIdx.x * 64;
  int r = blockIdx.y * 256 + tid;
  unsigned wplo[16], wphi[16], wzlo[16], wzhi[16];
  const uint4* wrow = (const uint4*)(wim + (size_t)r * 32);
#pragma unroll
  for (int i = 0; i < 16; i++) {
    uint4 w4 = wrow[i];
    wplo[i] = w4.x; wphi[i] = w4.y; wzlo[i] = w4.z; wzhi[i] = w4.w;
  }
  if (tid < 64) any[tid] = 0;
  __syncthreads();
  unsigned accor = 0;
#pragma unroll
  for (int i = 0; i < 4; i++) {
    int idx = tid * 4 + i;  // 0..1023 uint4 slots, straight copy
    uint4 v = ((const uint4*)(xm + (size_t)bt0 * 32))[idx];
    lx[idx] = v;
    accor |= v.z | v.w;  // nonzero-mask halves
  }
  if (accor) atomicOr(&any[tid >> 2], 1u);  // 4 threads per bt row
  __syncthreads();
  for (int bt = 0; bt < 64; bt++) {
    int k = 0;
    if (any[bt]) {
      const uint4* hx = lx + bt * 16;
      int sb = 0, sn = 0;
#pragma unroll
      for (int i = 0; i < 16; i++) {
        uint4 h = hx[i];  // broadcast ds_read_b128
        unsigned blo = h.z & wzlo[i];
        unsigned bhi = h.w & wzhi[i];
        unsigned nlo = (h.x ^ wplo[i]) & blo;
        unsigned nhi = (h.y ^ wphi[i]) & bhi;
        sb += __popc(blo) + __popc(bhi);
        sn += __popc(nlo) + __popc(nhi);
      }
      k = sb - 2 * sn;
    }
    nbuf[(size_t)(bt0 + bt) * 1024 + r] = (short)k;
  }
}

// ---- fused 3-stage pipeline ----------------------------------------------

static __device__ __forceinline__ int ldflag(const int* p) {
  return __hip_atomic_load(p, __ATOMIC_RELAXED, __HIP_MEMORY_SCOPE_AGENT);
}
static __device__ __forceinline__ void stflag(int* p, int v) {
  __hip_atomic_store(p, v, __ATOMIC_RELAXED, __HIP_MEMORY_SCOPE_AGENT);
}
static __device__ __forceinline__ unsigned long long ldu64(const unsigned long long* p) {
  return __hip_atomic_load(p, __ATOMIC_RELAXED, __HIP_MEMORY_SCOPE_AGENT);
}
static __device__ __forceinline__ int lds16(const short* p) {
  return (int)__hip_atomic_load(p, __ATOMIC_RELAXED, __HIP_MEMORY_SCOPE_AGENT);
}
static __device__ __forceinline__ void stu64(unsigned long long* p, unsigned long long v) {
  __hip_atomic_store(p, v, __ATOMIC_RELAXED, __HIP_MEMORY_SCOPE_AGENT);
}

// load one packed weight row (16 uint4) into 4 unrolled arrays (plain C --
// residency comes from keeping scheduler pressure below the 128 cap)
#define WROW_LOAD(SRC)                                                     \
  unsigned wplo[16], wphi[16], wzlo[16], wzhi[16];                         \
  _Pragma("unroll")                                                        \
  for (int _i = 0; _i < 16; _i++) {                                        \
    uint4 _w4 = (SRC)[_i];                                                 \
    wplo[_i] = _w4.x; wphi[_i] = _w4.y;                                    \
    wzlo[_i] = _w4.z; wzhi[_i] = _w4.w;                                    \
  }

// bit-dot over 16 h-quads (broadcast ds_read_b128) vs register weights.
// sched_barrier(0) per iteration: stops the pre-RA scheduler from
// clustering all 16 ds_reads (the pressure spike that forced weight
// sinking in R0-R3). Max 1 h-quad live => ~100 regs total demand.
#define DOT16(HQ, SB, SN)                                                  \
  do {                                                                     \
    int _b0 = 0, _b1 = 0, _n0 = 0, _n1 = 0;                                \
    _Pragma("unroll")                                                      \
    for (int _i = 0; _i < 16; _i++) {                                      \
      uint4 _h = (HQ)[_i]; /* broadcast ds_read_b128 (uniform addr) */     \
      unsigned _blo = _h.z & wzlo[_i];                                     \
      unsigned _bhi = _h.w & wzhi[_i];                                     \
      unsigned _nlo = (_h.x ^ wplo[_i]) & _blo;                            \
      unsigned _nhi = (_h.y ^ wphi[_i]) & _bhi;                            \
      if (_i & 1) { _b1 += __popc(_blo); _b1 += __popc(_bhi);              \
                    _n1 += __popc(_nlo); _n1 += __popc(_nhi); }            \
      else        { _b0 += __popc(_blo); _b0 += __popc(_bhi);              \
                    _n0 += __popc(_nlo); _n0 += __popc(_nhi); }            \
      __builtin_amdgcn_sched_barrier(0);                                   \
    }                                                                      \
    SB = _b0 + _b1; SN = _n0 + _n1;                                        \
  } while (0)

// integer thresholds reproducing the f64 predicate for one bias
static __device__ __forceinline__ void mk_thresh(double bias, int& kp, int& km) {
  kp = (int)ceil((0.5 - bias) * 10.0);
  while ((double)kp * 0.1 + bias <= 0.5) kp++;
  while ((double)(kp - 1) * 0.1 + bias > 0.5) kp--;
  km = (int)floor((-0.5 - bias) * 10.0);
  while ((double)km * 0.1 + bias >= -0.5) km--;
  while ((double)(km + 1) * 0.1 + bias < -0.5) km++;
}

// ROLE 0 = layer-0 recur (producer of x_t); ROLE 2 = layer-1 recur (consumer)
template <int ROLE>
static __device__ __forceinline__ void recur_stage(
    uint4 (*shb)[16], const short* nbuf,
    const unsigned long long* __restrict__ whm,
    const void* __restrict__ bih, const void* __restrict__ bhh,
    int isf32, int layer, int b, int r,
    unsigned long long* xrow,              // ROLE 0 only
    int* flagsA, int* flagsB,
    unsigned long long* __restrict__ hidm) {
  const uint4* wrow = (const uint4*)(whm + (size_t)(layer * 1024 + r) * 32);
  WROW_LOAD(wrow)
  size_t boff = (size_t)layer * 1024 + r;
  double bias = (double)loadw(bih, boff, isf32) + (double)loadw(bhh, boff, isf32);
  int kp, km;
  mk_thresh(bias, kp, km);

  if (r < 32) ((unsigned long long*)shb)[r] = 0;  // zero buffer 0
  const short* nrow = nbuf + (size_t)b * 512 * 1024 + r;
  int wv = r >> 6;
  bool l0 = (r & 63) == 0;
  int fb = 0;   // ROLE 2: cached flagsB
  int* flagsAp = flagsA + b * FLAG_STRIDE;
  int* flagsBp = flagsB + b * FLAG_STRIDE;
  int nin, nin1;
  if (ROLE == 0) {  // pre-pass data: plain loads fine
    nin  = (int)nrow[0];
    nin1 = (int)nrow[1024];
  } else {
    while ((fb = ldflag(flagsBp)) < 2) {}
    // data loads control-dependent on flag value => ordered, no acquire
    nin  = lds16(nrow);
    nin1 = lds16(nrow + 1024);
  }
  __syncthreads();
  int pb = 0;
  unsigned long long plo = 0, phi = 0;  // ROLE 0, l0 lanes: deferred x words
  for (int t = 0; t < 512; t++) {
    // ---- top of step: issue ALL memory ops (acks covered by the dot) ----
    if (ROLE == 0 && l0 && t > 0) {  // deferred store of x_{t-1}
      stu64(xrow + (size_t)(t - 1) * 32 + 2 * wv, plo);
      stu64(xrow + (size_t)(t - 1) * 32 + 2 * wv + 1, phi);
    }
    int nin2 = 0;
    bool got = true;
    if (t < 510) {  // distance-2 prefetch of n_{t+2}
      if (ROLE == 0) {
        nin2 = (int)nrow[(size_t)(t + 2) * 1024];
      } else {
        if (fb < t + 3) fb = ldflag(flagsBp);
        got = (fb >= t + 3);
        if (got) nin2 = lds16(nrow + (size_t)(t + 2) * 1024);
      }
    }
    // ---- dot over current h ----
    const uint4* Hq = shb[pb];
    int sb, sn;
    DOT16(Hq, sb, sn);
    int k = nin + sb - 2 * sn;
    unsigned long long bp = __ballot(k >= kp);
    unsigned long long bm = __ballot(k <= km);
    unsigned long long bz = bp | bm;
    if (l0) {
      uint4 o;
      o.x = (unsigned)bp; o.y = (unsigned)(bp >> 32);
      o.z = (unsigned)bz; o.w = (unsigned)(bz >> 32);
      shb[pb ^ 1][wv] = o;
      plo = bp; phi = bz;  // defer global store to next step
    }
    if (ROLE == 2 && t < 510 && !got) {  // cold path: pipeline fill only
      while ((fb = ldflag(flagsBp)) < t + 3) {}
      nin2 = lds16(nrow + (size_t)(t + 2) * 1024);
    }
    __syncthreads();  // implicit vmcnt(0)+lgkmcnt(0): stores/loads drained
    // publish AFTER barrier: all waves' stores of x[<=t-1] globally visible.
    if (ROLE == 0 && r == 0 && t > 0) stflag(flagsAp, t);
    pb ^= 1;
    nin = nin1;
    nin1 = nin2;
  }
  if (ROLE == 0) {  // commit x[511], then final publish
    if (l0) {
      stu64(xrow + (size_t)511 * 32 + 2 * wv, plo);
      stu64(xrow + (size_t)511 * 32 + 2 * wv + 1, phi);
    }
    __syncthreads();  // drains the stores
    if (r == 0) stflag(flagsAp, 512);
  }
  if (r < 16) {  // final h is in shb[pb]
    uint4 h = shb[pb][r];
    size_t ho = (size_t)(layer * 64 + b) * 32;
    hidm[ho + 2 * r]     = ((unsigned long long)h.y << 32) | h.x;
    hidm[ho + 2 * r + 1] = ((unsigned long long)h.w << 32) | h.z;
  }
}

__global__ __launch_bounds__(1024, 4) void k_pipe(
    short* nbuf, unsigned long long* x0,
    const unsigned long long* __restrict__ wim,
    const unsigned long long* __restrict__ whm,
    const void* __restrict__ bih, const void* __restrict__ bhh,
    const int* __restrict__ flags, int* flagsA, int* flagsB,
    unsigned long long* __restrict__ hidm) {
  __shared__ __align__(16) uint4 shb[2][16];
  int role = blockIdx.x % 3;  // interleave roles across XCDs
  int b = blockIdx.x / 3;
  int r = threadIdx.x;
  int isf32 = flags[0];
  if (role == 0) {
    recur_stage<0>(shb, nbuf, whm, bih, bhh, isf32, 0, b, r,
                   x0 + (size_t)b * 512 * 32, flagsA, flagsB, hidm);
  } else if (role == 1) {
    // ---- stage B: layer-1 input bit-GEMM, trailing A by ~4 steps ----------
    // Invariants at top of step t: LDS buf[t&1] = x_t; vnext = x_{t+1};
    // v2 = x_{t+2} (r<32); ncur = n_{t-1} (t>0, in register).
    const uint4* wrow = (const uint4*)(wim + (size_t)(1024 + r) * 32);
    WROW_LOAD(wrow)
    const unsigned long long* xsrc = x0 + (size_t)b * 512 * 32;
    short* nout = nbuf + (size_t)b * 512 * 1024 + r;
    int* flagsAp = flagsA + b * FLAG_STRIDE;
    int* flagsBp = flagsB + b * FLAG_STRIDE;
    int fa = 0;
    unsigned long long vnext = 0, v2 = 0;
    if (r < 32) {  // prologue: x_0 -> buf[0]; x_1, x_2 -> regs
      while ((fa = ldflag(flagsAp)) < 1) {}
      ((unsigned long long*)(shb[0]))[r] = ldu64(xsrc + r);
      while (fa < 2) { fa = ldflag(flagsAp); }
      vnext = ldu64(xsrc + 32 + r);
      while (fa < 3) { fa = ldflag(flagsAp); }
      v2 = ldu64(xsrc + 64 + r);
    }
    __syncthreads();
    short ncur = 0;
    for (int t = 0; t < 512; t++) {
      // top of step: LDS-write x_{t+1}; store n_{t-1}; issue load x_{t+3}
      if (r < 32 && t < 511) ((unsigned long long*)(shb[(t + 1) & 1]))[r] = vnext;
      if (t > 0)
        __hip_atomic_store(nout + (size_t)(t - 1) * 1024, ncur,
                           __ATOMIC_RELAXED, __HIP_MEMORY_SCOPE_AGENT);
      bool got = true;
      unsigned long long v3 = 0;
      if (r < 32 && t < 509) {  // distance-3 prefetch
        if (fa < t + 4) fa = ldflag(flagsAp);
        got = (fa >= t + 4);
        if (got) v3 = ldu64(xsrc + (size_t)(t + 3) * 32 + r);
      }
      const uint4* hx = shb[t & 1];
      int sb, sn;
      DOT16(hx, sb, sn);
      if (r < 32 && t < 509 && !got) {  // cold path: pipeline fill only
        while ((fa = ldflag(flagsAp)) < t + 4) {}
        v3 = ldu64(xsrc + (size_t)(t + 3) * 32 + r);
      }
      __syncthreads();   // drains n-store + x-load; buf[(t+1)&1] visible
      if (r == 0 && t > 0) stflag(flagsBp, t);  // n[0..t-1] committed
      ncur = (short)(sb - 2 * sn);
      vnext = v2;
      v2 = v3;
    }
    // epilogue: commit n_511, publish full
    __hip_atomic_store(nout + (size_t)511 * 1024, ncur,
                       __ATOMIC_RELAXED, __HIP_MEMORY_SCOPE_AGENT);
    __syncthreads();
    if (r == 0) stflag(flagsBp, 512);
  } else {
    recur_stage<2>(shb, nbuf, whm, bih, bhh, isf32, 1, b, r,
                   (unsigned long long*)0, flagsA, flagsB, hidm);
  }
}

__global__ __launch_bounds__(64) void k_fc(const unsigned long long* __restrict__ hidm,
    const unsigned long long* __restrict__ fcm, const int* __restrict__ flags,
    void* __restrict__ out) {
  int isf32 = flags[0];
  int lb = blockIdx.x, lane = threadIdx.x;
  unsigned long long hp = 0, hz = 0;
  if (lane < 16) {
    hp = hidm[lb * 32 + 2 * lane];
    hz = hidm[lb * 32 + 2 * lane + 1];
  }
#pragma unroll
  for (int o = 0; o < 4; o++) {
    int k = 0;
    if (lane < 16) {
      unsigned long long wp = fcm[o * 32 + 2 * lane], wz = fcm[o * 32 + 2 * lane + 1];
      unsigned long long both = hz & wz;
      unsigned long long neg = both & (hp ^ wp);
      k = __popcll(both) - 2 * __popcll(neg);
    }
    for (int off = 8; off > 0; off >>= 1) k += __shfl_down(k, off);
    if (lane == 0) {
      float v = (float)((double)k * 0.1);
      if (isf32) ((float*)out)[lb * 4 + o] = v;
      else       ((unsigned short*)out)[lb * 4 + o] = f2bf(v);
    }
  }
}

extern "C" void kernel_launch(void* const* d_in, const int* in_sizes, int n_in,
                              void* d_out, int out_size, void* d_ws, size_t ws_size,
                              hipStream_t stream) {
  (void)in_sizes; (void)n_in; (void)out_size; (void)ws_size;
  const int* text = (const int*)d_in[0];
  // d_in[1] text_lengths: unused by the reference
  const void* emb = d_in[2];
  const void* Wih = d_in[3];
  const void* Whh = d_in[4];
  const void* bih = d_in[5];
  const void* bhh = d_in[6];
  const void* fcw = d_in[7];

  // workspace layout (~73 MB)
  char* ws = (char*)d_ws;
  int* flags = (int*)(ws);
  unsigned* mab = (unsigned*)(ws + 64);
  int* flagsA = (int*)(ws + 1024);   // 64 flags, stride 16 ints (4 KB)
  int* flagsB = (int*)(ws + 5120);   // 64 flags, stride 16 ints (4 KB)
  size_t off = 16384;
  unsigned long long* x0 = (unsigned long long*)(ws + off);  off += (size_t)32768 * 256;
  unsigned long long* wim = (unsigned long long*)(ws + off); off += (size_t)2048 * 256;
  unsigned long long* whm = (unsigned long long*)(ws + off); off += (size_t)2048 * 256;
  unsigned long long* fcm = (unsigned long long*)(ws + off); off += (size_t)4 * 256;
  unsigned long long* hidm = (unsigned long long*)(ws + off); off += (size_t)128 * 256;
  short* nbuf = (short*)(ws + off);                          off += (size_t)32768 * 1024 * 2;

  hipMemsetAsync(ws, 0, 16384, stream);  // flags, mab, flagsA, flagsB
  k_detect<<<256, 256, 0, stream>>>((const unsigned short*)emb, text, flags);
  k_maxabs<<<2048, 256, 0, stream>>>((const uint4*)emb, flags, mab);
  k_tern_rows<<<4100, 1024, 0, stream>>>(Wih, Whh, fcw, flags, wim, whm, fcm);
  k_embed<<<32768, 1024, 0, stream>>>(text, emb, flags, mab, x0);
  // layer-0 input gemm (x0 consumed; region then reused as layer-0 x-out)
  k_bitgemm<<<dim3(512, 4), 256, 0, stream>>>(x0, wim, nbuf);
  // fused pipeline: layer-0 recur || layer-1 bitgemm || layer-1 recur
  k_pipe<<<192, 1024, 0, stream>>>(nbuf, x0, wim, whm, bih, bhh, flags,
                                   flagsA, flagsB, hidm);
  k_fc<<<128, 64, 0, stream>>>(hidm, fcm, flags, d_out);
}

// Round 8
// 1965.942 us; speedup vs baseline: 3.3245x; 1.0689x over previous
//
#include <hip/hip_runtime.h>
#include <cstdint>
#include <cstddef>

// ---------------------------------------------------------------------------
// QRNN 2-bit forward, exact ternary-integer formulation.
// flags[0]=1 -> floats are f32 (else bf16); flags[1]=1 -> text is int64.
// Ternary vectors (len 1024) bit-packed as 32 u64: [2i]=plus, [2i+1]=nonzero.
// As uint4 i: (p.lo, p.hi, z.lo, z.hi) for elements 64i..64i+63.
// dot: both=hz&wz; neg=both&(hp^wp); k=popc(both)-2*popc(neg)
// Decision v = k*0.1+bias vs +-0.5 is monotone in k -> precomputed integer
// thresholds kp/km reproduce the f64 predicate bit-exactly.
//
// R-pipeline (k_pipe, 192 blocks = 64 A + 64 B + 64 C):
//   A = layer-0 recur (produces x_t), B = layer-1 input bit-GEMM (x_t -> n_t,
//   in-place into nbuf), C = layer-1 recur (consumes n_t).
// Fenceless handoff (R2, validated): all cross-stage data stores/loads are
// RELAXED+AGENT (sc0 sc1 -> write/read-through the IC, never dirty in L2 =>
// no wbl2). Flags are RELAXED agent stores issued AFTER __syncthreads()
// (the barrier's implicit vmcnt(0) drain => all waves' IC stores visible
// first). Consumer data loads are control-dependent on observed flag values
// => ordered without acquire fences. Same-address flag stores separated by
// barriers. Dependency graph acyclic; 192 blocks co-resident => no deadlock.
//
// R8: WEIGHT RESIDENCY VIA OCCUPANCY CLAMP.
// The remat saga resolved: R0 allocated 48 VGPRs (10 waves/EU budget),
// R3/R7 64 (8 waves/EU) -- the backend CHOOSES a high-occupancy target by
// heuristic (launch_bounds' 2nd arg is only a MINIMUM) and remats the
// loop-invariant __restrict__ weight loads to fit that self-imposed budget
// (16x buffer_load_dwordx4/thread/step = 256 KB/CU-step L2 stream ~=
// 4400 cy = the invariant floor). Demand (~103 regs) always fit in 128.
// R4/R5 asm pins -> scratch thrash; R6 512-thr -> half occupancy; R7
// sched_barrier -> serialized dot (VALUBusy 59->27, still remat).
// Fix: __attribute__((amdgpu_waves_per_eu(4,4))) pins min=max=4 waves/EU
// => 128-VGPR budget is mandatory => no remat incentive, weights resident.
// Tell-tale: VGPR_Count >= 100 and FETCH stays ~85 MB (no scratch).
// ---------------------------------------------------------------------------

#define FLAG_STRIDE 16  // one flag per 64 B to avoid line contention

static __device__ __forceinline__ float bf2f(unsigned short b) {
  return __uint_as_float(((unsigned)b) << 16);
}
static __device__ __forceinline__ unsigned short f2bf(float f) {
  unsigned u = __float_as_uint(f);
  u = (u + 0x7FFFu + ((u >> 16) & 1u)) >> 16;  // RNE
  return (unsigned short)u;
}
static __device__ __forceinline__ float loadw(const void* p, size_t i, int isf32) {
  return isf32 ? ((const float*)p)[i] : bf2f(((const unsigned short*)p)[i]);
}

__global__ __launch_bounds__(256) void k_detect(const unsigned short* __restrict__ embu,
                                                const int* __restrict__ text,
                                                int* __restrict__ flags) {
  int i = blockIdx.x * 256 + threadIdx.x;  // 65536 u16 samples: valid in either layout
  unsigned e = (embu[i] >> 7) & 0xFFu;     // bf16-view exponent field
  unsigned long long b = __ballot(e >= 127u);
  if ((threadIdx.x & 63) == 0 && b) atomicOr(&flags[0], 1);
  if (blockIdx.x == 0 && threadIdx.x == 0) {
    int allz = 1;
    for (int j = 0; j < 32; j++)
      if (text[2 * j + 1] != 0) allz = 0;   // first 256 B: valid in either layout
    flags[1] = allz;
  }
}

// vectorized max|emb|
__global__ __launch_bounds__(256) void k_maxabs(const uint4* __restrict__ w,
                                                const int* __restrict__ flags,
                                                unsigned* __restrict__ out) {
  int isf32 = flags[0];
  int n16 = isf32 ? 7680000 : 3840000;  // 30720000 elems / (4 or 8 per uint4)
  float mf = 0.f;
  unsigned mb = 0;
  int i = blockIdx.x * blockDim.x + threadIdx.x;
  int stride = gridDim.x * blockDim.x;
  if (isf32) {
    for (; i < n16; i += stride) {
      uint4 v = w[i];
      mf = fmaxf(mf, fabsf(__uint_as_float(v.x)));
      mf = fmaxf(mf, fabsf(__uint_as_float(v.y)));
      mf = fmaxf(mf, fabsf(__uint_as_float(v.z)));
      mf = fmaxf(mf, fabsf(__uint_as_float(v.w)));
    }
  } else {
    for (; i < n16; i += stride) {
      uint4 v = w[i];
      unsigned a;
      a = v.x & 0x7FFF7FFFu; mb = max(mb, a & 0xFFFFu); mb = max(mb, a >> 16);
      a = v.y & 0x7FFF7FFFu; mb = max(mb, a & 0xFFFFu); mb = max(mb, a >> 16);
      a = v.z & 0x7FFF7FFFu; mb = max(mb, a & 0xFFFFu); mb = max(mb, a >> 16);
      a = v.w & 0x7FFF7FFFu; mb = max(mb, a & 0xFFFFu); mb = max(mb, a >> 16);
    }
    mf = bf2f((unsigned short)mb);
  }
  for (int off = 32; off > 0; off >>= 1) mf = fmaxf(mf, __shfl_down(mf, off));
  __shared__ float red[4];
  if ((threadIdx.x & 63) == 0) red[threadIdx.x >> 6] = mf;
  __syncthreads();
  if (threadIdx.x == 0) {
    float b = fmaxf(fmaxf(red[0], red[1]), fmaxf(red[2], red[3]));
    atomicMax(out, __float_as_uint(b));  // b >= 0: bit pattern order-monotone
  }
}

__global__ __launch_bounds__(1024) void k_tern_rows(
    const void* __restrict__ Wih, const void* __restrict__ Whh,
    const void* __restrict__ fcw, const int* __restrict__ flags,
    unsigned long long* __restrict__ wim, unsigned long long* __restrict__ whm,
    unsigned long long* __restrict__ fcm) {
  int isf32 = flags[0];
  int b = blockIdx.x;  // 0..4099
  const void* src;
  size_t rowoff;
  unsigned long long* dst;
  if (b < 2048)      { src = Wih; rowoff = (size_t)b * 1024; dst = wim + (size_t)b * 32; }
  else if (b < 4096) { int r = b - 2048; src = Whh; rowoff = (size_t)r * 1024; dst = whm + (size_t)r * 32; }
  else               { int r = b - 4096; src = fcw; rowoff = (size_t)r * 1024; dst = fcm + (size_t)r * 32; }
  double w = (double)loadw(src, rowoff + threadIdx.x, isf32);
  unsigned long long bp = __ballot(w > 0.05);   // THR*W_SCALE, exact f64
  unsigned long long bm = __ballot(w < -0.05);
  if ((threadIdx.x & 63) == 0) {
    int wv = threadIdx.x >> 6;
    dst[2 * wv] = bp;
    dst[2 * wv + 1] = bp | bm;
  }
}

__global__ __launch_bounds__(1024) void k_embed(const int* __restrict__ text,
    const void* __restrict__ emb, const int* __restrict__ flags,
    const unsigned* __restrict__ mab, unsigned long long* __restrict__ x0) {
  int isf32 = flags[0], i64 = flags[1];
  int bt = blockIdx.x;
  long long tok = i64 ? ((const long long*)text)[bt] : (long long)text[bt];
  double ma = (double)__uint_as_float(*mab);
  float s = (float)exp2(ceil(log2(ma)));           // pow-2 scale (int_max = 1)
  float inv_s = 1.0f / s;                          // exact (pow-2)
  float w = loadw(emb, (size_t)tok * 1024 + threadIdx.x, isf32);
  float q = rintf(w * inv_s);                      // exact mul, half-even
  q = fminf(fmaxf(q, -2.0f), 1.0f);                // clip [-2, 1] (bw = 2)
  float val = q * s;                               // exact
  int code = (val > 0.5f) ? 1 : ((val < -0.5f) ? -1 : 0);
  unsigned long long bp = __ballot(code == 1);
  unsigned long long bm = __ballot(code == -1);
  if ((threadIdx.x & 63) == 0) {
    int wv = threadIdx.x >> 6;
    x0[(size_t)bt * 32 + 2 * wv] = bp;
    x0[(size_t)bt * 32 + 2 * wv + 1] = bp | bm;
  }
}

// ---- bit-GEMM (layer-0 pre-pass): n[bt][r] = <x_row[bt], Wi_row[r]> -------
// R0 form (weight remat from L2 per bt-iter is fine for a one-shot pass).
__global__ __launch_bounds__(256, 4) void k_bitgemm(const unsigned long long* __restrict__ xm,
    const unsigned long long* __restrict__ wim, short* __restrict__ nbuf) {
  __shared__ __align__(16) uint4 lx[64 * 16];  // [bt][i] = (p.lo,p.hi,z.lo,z.hi)
  __shared__ unsigned any[64];
  int tid = threadIdx.x;
  int bt0 = blockIdx.x * 64;
  int r = blockIdx.y * 256 + tid;
  unsigned wplo[16], wphi[16], wzlo[16], wzhi[16];
  const uint4* wrow = (const uint4*)(wim + (size_t)r * 32);
#pragma unroll
  for (int i = 0; i < 16; i++) {
    uint4 w4 = wrow[i];
    wplo[i] = w4.x; wphi[i] = w4.y; wzlo[i] = w4.z; wzhi[i] = w4.w;
  }
  if (tid < 64) any[tid] = 0;
  __syncthreads();
  unsigned accor = 0;
#pragma unroll
  for (int i = 0; i < 4; i++) {
    int idx = tid * 4 + i;  // 0..1023 uint4 slots, straight copy
    uint4 v = ((const uint4*)(xm + (size_t)bt0 * 32))[idx];
    lx[idx] = v;
    accor |= v.z | v.w;  // nonzero-mask halves
  }
  if (accor) atomicOr(&any[tid >> 2], 1u);  // 4 threads per bt row
  __syncthreads();
  for (int bt = 0; bt < 64; bt++) {
    int k = 0;
    if (any[bt]) {
      const uint4* hx = lx + bt * 16;
      int sb = 0, sn = 0;
#pragma unroll
      for (int i = 0; i < 16; i++) {
        uint4 h = hx[i];  // broadcast ds_read_b128
        unsigned blo = h.z & wzlo[i];
        unsigned bhi = h.w & wzhi[i];
        unsigned nlo = (h.x ^ wplo[i]) & blo;
        unsigned nhi = (h.y ^ wphi[i]) & bhi;
        sb += __popc(blo) + __popc(bhi);
        sn += __popc(nlo) + __popc(nhi);
      }
      k = sb - 2 * sn;
    }
    nbuf[(size_t)(bt0 + bt) * 1024 + r] = (short)k;
  }
}

// ---- fused 3-stage pipeline ----------------------------------------------

static __device__ __forceinline__ int ldflag(const int* p) {
  return __hip_atomic_load(p, __ATOMIC_RELAXED, __HIP_MEMORY_SCOPE_AGENT);
}
static __device__ __forceinline__ void stflag(int* p, int v) {
  __hip_atomic_store(p, v, __ATOMIC_RELAXED, __HIP_MEMORY_SCOPE_AGENT);
}
static __device__ __forceinline__ unsigned long long ldu64(const unsigned long long* p) {
  return __hip_atomic_load(p, __ATOMIC_RELAXED, __HIP_MEMORY_SCOPE_AGENT);
}
static __device__ __forceinline__ int lds16(const short* p) {
  return (int)__hip_atomic_load(p, __ATOMIC_RELAXED, __HIP_MEMORY_SCOPE_AGENT);
}
static __device__ __forceinline__ void stu64(unsigned long long* p, unsigned long long v) {
  __hip_atomic_store(p, v, __ATOMIC_RELAXED, __HIP_MEMORY_SCOPE_AGENT);
}

// load one packed weight row (16 uint4) into 4 unrolled arrays (plain C --
// residency comes from the amdgpu_waves_per_eu(4,4) 128-reg budget)
#define WROW_LOAD(SRC)                                                     \
  unsigned wplo[16], wphi[16], wzlo[16], wzhi[16];                         \
  _Pragma("unroll")                                                        \
  for (int _i = 0; _i < 16; _i++) {                                        \
    uint4 _w4 = (SRC)[_i];                                                 \
    wplo[_i] = _w4.x; wphi[_i] = _w4.y;                                    \
    wzlo[_i] = _w4.z; wzhi[_i] = _w4.w;                                    \
  }

// bit-dot over 16 h-quads (broadcast ds_read_b128) vs register weights.
// Split accumulators; compiler schedules freely (R7's sched_barrier
// serialized the dot and regressed -- TLP at 4 waves/SIMD hides latency).
#define DOT16(HQ, SB, SN)                                                  \
  do {                                                                     \
    int _b0 = 0, _b1 = 0, _n0 = 0, _n1 = 0;                                \
    _Pragma("unroll")                                                      \
    for (int _i = 0; _i < 16; _i++) {                                      \
      uint4 _h = (HQ)[_i]; /* broadcast ds_read_b128 (uniform addr) */     \
      unsigned _blo = _h.z & wzlo[_i];                                     \
      unsigned _bhi = _h.w & wzhi[_i];                                     \
      unsigned _nlo = (_h.x ^ wplo[_i]) & _blo;                            \
      unsigned _nhi = (_h.y ^ wphi[_i]) & _bhi;                            \
      if (_i & 1) { _b1 += __popc(_blo); _b1 += __popc(_bhi);              \
                    _n1 += __popc(_nlo); _n1 += __popc(_nhi); }            \
      else        { _b0 += __popc(_blo); _b0 += __popc(_bhi);              \
                    _n0 += __popc(_nlo); _n0 += __popc(_nhi); }            \
    }                                                                      \
    SB = _b0 + _b1; SN = _n0 + _n1;                                        \
  } while (0)

// integer thresholds reproducing the f64 predicate for one bias
static __device__ __forceinline__ void mk_thresh(double bias, int& kp, int& km) {
  kp = (int)ceil((0.5 - bias) * 10.0);
  while ((double)kp * 0.1 + bias <= 0.5) kp++;
  while ((double)(kp - 1) * 0.1 + bias > 0.5) kp--;
  km = (int)floor((-0.5 - bias) * 10.0);
  while ((double)km * 0.1 + bias >= -0.5) km--;
  while ((double)(km + 1) * 0.1 + bias < -0.5) km++;
}

// ROLE 0 = layer-0 recur (producer of x_t); ROLE 2 = layer-1 recur (consumer)
template <int ROLE>
static __device__ __forceinline__ void recur_stage(
    uint4 (*shb)[16], const short* nbuf,
    const unsigned long long* __restrict__ whm,
    const void* __restrict__ bih, const void* __restrict__ bhh,
    int isf32, int layer, int b, int r,
    unsigned long long* xrow,              // ROLE 0 only
    int* flagsA, int* flagsB,
    unsigned long long* __restrict__ hidm) {
  const uint4* wrow = (const uint4*)(whm + (size_t)(layer * 1024 + r) * 32);
  WROW_LOAD(wrow)
  size_t boff = (size_t)layer * 1024 + r;
  double bias = (double)loadw(bih, boff, isf32) + (double)loadw(bhh, boff, isf32);
  int kp, km;
  mk_thresh(bias, kp, km);

  if (r < 32) ((unsigned long long*)shb)[r] = 0;  // zero buffer 0
  const short* nrow = nbuf + (size_t)b * 512 * 1024 + r;
  int wv = r >> 6;
  bool l0 = (r & 63) == 0;
  int fb = 0;   // ROLE 2: cached flagsB
  int* flagsAp = flagsA + b * FLAG_STRIDE;
  int* flagsBp = flagsB + b * FLAG_STRIDE;
  int nin, nin1;
  if (ROLE == 0) {  // pre-pass data: plain loads fine
    nin  = (int)nrow[0];
    nin1 = (int)nrow[1024];
  } else {
    while ((fb = ldflag(flagsBp)) < 2) {}
    // data loads control-dependent on flag value => ordered, no acquire
    nin  = lds16(nrow);
    nin1 = lds16(nrow + 1024);
  }
  __syncthreads();
  int pb = 0;
  unsigned long long plo = 0, phi = 0;  // ROLE 0, l0 lanes: deferred x words
  for (int t = 0; t < 512; t++) {
    // ---- top of step: issue ALL memory ops (acks covered by the dot) ----
    if (ROLE == 0 && l0 && t > 0) {  // deferred store of x_{t-1}
      stu64(xrow + (size_t)(t - 1) * 32 + 2 * wv, plo);
      stu64(xrow + (size_t)(t - 1) * 32 + 2 * wv + 1, phi);
    }
    int nin2 = 0;
    bool got = true;
    if (t < 510) {  // distance-2 prefetch of n_{t+2}
      if (ROLE == 0) {
        nin2 = (int)nrow[(size_t)(t + 2) * 1024];
      } else {
        if (fb < t + 3) fb = ldflag(flagsBp);
        got = (fb >= t + 3);
        if (got) nin2 = lds16(nrow + (size_t)(t + 2) * 1024);
      }
    }
    // ---- dot over current h ----
    const uint4* Hq = shb[pb];
    int sb, sn;
    DOT16(Hq, sb, sn);
    int k = nin + sb - 2 * sn;
    unsigned long long bp = __ballot(k >= kp);
    unsigned long long bm = __ballot(k <= km);
    unsigned long long bz = bp | bm;
    if (l0) {
      uint4 o;
      o.x = (unsigned)bp; o.y = (unsigned)(bp >> 32);
      o.z = (unsigned)bz; o.w = (unsigned)(bz >> 32);
      shb[pb ^ 1][wv] = o;
      plo = bp; phi = bz;  // defer global store to next step
    }
    if (ROLE == 2 && t < 510 && !got) {  // cold path: pipeline fill only
      while ((fb = ldflag(flagsBp)) < t + 3) {}
      nin2 = lds16(nrow + (size_t)(t + 2) * 1024);
    }
    __syncthreads();  // implicit vmcnt(0)+lgkmcnt(0): stores/loads drained
    // publish AFTER barrier: all waves' stores of x[<=t-1] globally visible.
    if (ROLE == 0 && r == 0 && t > 0) stflag(flagsAp, t);
    pb ^= 1;
    nin = nin1;
    nin1 = nin2;
  }
  if (ROLE == 0) {  // commit x[511], then final publish
    if (l0) {
      stu64(xrow + (size_t)511 * 32 + 2 * wv, plo);
      stu64(xrow + (size_t)511 * 32 + 2 * wv + 1, phi);
    }
    __syncthreads();  // drains the stores
    if (r == 0) stflag(flagsAp, 512);
  }
  if (r < 16) {  // final h is in shb[pb]
    uint4 h = shb[pb][r];
    size_t ho = (size_t)(layer * 64 + b) * 32;
    hidm[ho + 2 * r]     = ((unsigned long long)h.y << 32) | h.x;
    hidm[ho + 2 * r + 1] = ((unsigned long long)h.w << 32) | h.z;
  }
}

__global__ __launch_bounds__(1024)
__attribute__((amdgpu_waves_per_eu(4, 4)))  // pin 4 waves/EU => 128-reg budget
void k_pipe(
    short* nbuf, unsigned long long* x0,
    const unsigned long long* __restrict__ wim,
    const unsigned long long* __restrict__ whm,
    const void* __restrict__ bih, const void* __restrict__ bhh,
    const int* __restrict__ flags, int* flagsA, int* flagsB,
    unsigned long long* __restrict__ hidm) {
  __shared__ __align__(16) uint4 shb[2][16];
  int role = blockIdx.x % 3;  // interleave roles across XCDs
  int b = blockIdx.x / 3;
  int r = threadIdx.x;
  int isf32 = flags[0];
  if (role == 0) {
    recur_stage<0>(shb, nbuf, whm, bih, bhh, isf32, 0, b, r,
                   x0 + (size_t)b * 512 * 32, flagsA, flagsB, hidm);
  } else if (role == 1) {
    // ---- stage B: layer-1 input bit-GEMM, trailing A by ~4 steps ----------
    // Invariants at top of step t: LDS buf[t&1] = x_t; vnext = x_{t+1};
    // v2 = x_{t+2} (r<32); ncur = n_{t-1} (t>0, in register).
    const uint4* wrow = (const uint4*)(wim + (size_t)(1024 + r) * 32);
    WROW_LOAD(wrow)
    const unsigned long long* xsrc = x0 + (size_t)b * 512 * 32;
    short* nout = nbuf + (size_t)b * 512 * 1024 + r;
    int* flagsAp = flagsA + b * FLAG_STRIDE;
    int* flagsBp = flagsB + b * FLAG_STRIDE;
    int fa = 0;
    unsigned long long vnext = 0, v2 = 0;
    if (r < 32) {  // prologue: x_0 -> buf[0]; x_1, x_2 -> regs
      while ((fa = ldflag(flagsAp)) < 1) {}
      ((unsigned long long*)(shb[0]))[r] = ldu64(xsrc + r);
      while (fa < 2) { fa = ldflag(flagsAp); }
      vnext = ldu64(xsrc + 32 + r);
      while (fa < 3) { fa = ldflag(flagsAp); }
      v2 = ldu64(xsrc + 64 + r);
    }
    __syncthreads();
    short ncur = 0;
    for (int t = 0; t < 512; t++) {
      // top of step: LDS-write x_{t+1}; store n_{t-1}; issue load x_{t+3}
      if (r < 32 && t < 511) ((unsigned long long*)(shb[(t + 1) & 1]))[r] = vnext;
      if (t > 0)
        __hip_atomic_store(nout + (size_t)(t - 1) * 1024, ncur,
                           __ATOMIC_RELAXED, __HIP_MEMORY_SCOPE_AGENT);
      bool got = true;
      unsigned long long v3 = 0;
      if (r < 32 && t < 509) {  // distance-3 prefetch
        if (fa < t + 4) fa = ldflag(flagsAp);
        got = (fa >= t + 4);
        if (got) v3 = ldu64(xsrc + (size_t)(t + 3) * 32 + r);
      }
      const uint4* hx = shb[t & 1];
      int sb, sn;
      DOT16(hx, sb, sn);
      if (r < 32 && t < 509 && !got) {  // cold path: pipeline fill only
        while ((fa = ldflag(flagsAp)) < t + 4) {}
        v3 = ldu64(xsrc + (size_t)(t + 3) * 32 + r);
      }
      __syncthreads();   // drains n-store + x-load; buf[(t+1)&1] visible
      if (r == 0 && t > 0) stflag(flagsBp, t);  // n[0..t-1] committed
      ncur = (short)(sb - 2 * sn);
      vnext = v2;
      v2 = v3;
    }
    // epilogue: commit n_511, publish full
    __hip_atomic_store(nout + (size_t)511 * 1024, ncur,
                       __ATOMIC_RELAXED, __HIP_MEMORY_SCOPE_AGENT);
    __syncthreads();
    if (r == 0) stflag(flagsBp, 512);
  } else {
    recur_stage<2>(shb, nbuf, whm, bih, bhh, isf32, 1, b, r,
                   (unsigned long long*)0, flagsA, flagsB, hidm);
  }
}

__global__ __launch_bounds__(64) void k_fc(const unsigned long long* __restrict__ hidm,
    const unsigned long long* __restrict__ fcm, const int* __restrict__ flags,
    void* __restrict__ out) {
  int isf32 = flags[0];
  int lb = blockIdx.x, lane = threadIdx.x;
  unsigned long long hp = 0, hz = 0;
  if (lane < 16) {
    hp = hidm[lb * 32 + 2 * lane];
    hz = hidm[lb * 32 + 2 * lane + 1];
  }
#pragma unroll
  for (int o = 0; o < 4; o++) {
    int k = 0;
    if (lane < 16) {
      unsigned long long wp = fcm[o * 32 + 2 * lane], wz = fcm[o * 32 + 2 * lane + 1];
      unsigned long long both = hz & wz;
      unsigned long long neg = both & (hp ^ wp);
      k = __popcll(both) - 2 * __popcll(neg);
    }
    for (int off = 8; off > 0; off >>= 1) k += __shfl_down(k, off);
    if (lane == 0) {
      float v = (float)((double)k * 0.1);
      if (isf32) ((float*)out)[lb * 4 + o] = v;
      else       ((unsigned short*)out)[lb * 4 + o] = f2bf(v);
    }
  }
}

extern "C" void kernel_launch(void* const* d_in, const int* in_sizes, int n_in,
                              void* d_out, int out_size, void* d_ws, size_t ws_size,
                              hipStream_t stream) {
  (void)in_sizes; (void)n_in; (void)out_size; (void)ws_size;
  const int* text = (const int*)d_in[0];
  // d_in[1] text_lengths: unused by the reference
  const void* emb = d_in[2];
  const void* Wih = d_in[3];
  const void* Whh = d_in[4];
  const void* bih = d_in[5];
  const void* bhh = d_in[6];
  const void* fcw = d_in[7];

  // workspace layout (~73 MB)
  char* ws = (char*)d_ws;
  int* flags = (int*)(ws);
  unsigned* mab = (unsigned*)(ws + 64);
  int* flagsA = (int*)(ws + 1024);   // 64 flags, stride 16 ints (4 KB)
  int* flagsB = (int*)(ws + 5120);   // 64 flags, stride 16 ints (4 KB)
  size_t off = 16384;
  unsigned long long* x0 = (unsigned long long*)(ws + off);  off += (size_t)32768 * 256;
  unsigned long long* wim = (unsigned long long*)(ws + off); off += (size_t)2048 * 256;
  unsigned long long* whm = (unsigned long long*)(ws + off); off += (size_t)2048 * 256;
  unsigned long long* fcm = (unsigned long long*)(ws + off); off += (size_t)4 * 256;
  unsigned long long* hidm = (unsigned long long*)(ws + off); off += (size_t)128 * 256;
  short* nbuf = (short*)(ws + off);                          off += (size_t)32768 * 1024 * 2;

  hipMemsetAsync(ws, 0, 16384, stream);  // flags, mab, flagsA, flagsB
  k_detect<<<256, 256, 0, stream>>>((const unsigned short*)emb, text, flags);
  k_maxabs<<<2048, 256, 0, stream>>>((const uint4*)emb, flags, mab);
  k_tern_rows<<<4100, 1024, 0, stream>>>(Wih, Whh, fcw, flags, wim, whm, fcm);
  k_embed<<<32768, 1024, 0, stream>>>(text, emb, flags, mab, x0);
  // layer-0 input gemm (x0 consumed; region then reused as layer-0 x-out)
  k_bitgemm<<<dim3(512, 4), 256, 0, stream>>>(x0, wim, nbuf);
  // fused pipeline: layer-0 recur || layer-1 bitgemm || layer-1 recur
  k_pipe<<<192, 1024, 0, stream>>>(nbuf, x0, wim, whm, bih, bhh, flags,
                                   flagsA, flagsB, hidm);
  k_fc<<<128, 64, 0, stream>>>(hidm, fcm, flags, d_out);
}